// Round 16
// baseline (528.981 us; speedup 1.0000x reference)
//
#include <hip/hip_runtime.h>
#include <cstdint>
#include <cstddef>

#define H 4
#define DK 128
#define DV 256
#define NH 2
#define HID 1024
#define KSZ 4
#define NTOT 4608  // packed projection width: 512 q | 1024 k | 2048 v | 1024 g

typedef __bf16 bfx8 __attribute__((ext_vector_type(8)));
typedef float f32x4 __attribute__((ext_vector_type(4)));

__device__ __forceinline__ float wave_sum(float x) {
#pragma unroll
  for (int off = 1; off < 64; off <<= 1) x += __shfl_xor(x, off, 64);
  return x;
}

__device__ __forceinline__ ushort f2bf(float x) {
  uint u = __float_as_uint(x);
  return (ushort)((u + 0x7fffu + ((u >> 16) & 1u)) >> 16);
}

#define DPP_ADD(x, ctrl) \
  x += __int_as_float(__builtin_amdgcn_update_dpp(0, __float_as_int(x), ctrl, 0xf, 0xf, true))

// N independent full-wave64 sums (6-stage); results uniform via readlane(63)
template <int N>
__device__ __forceinline__ void dpp_reduce(float (&d)[N]) {
#pragma unroll
  for (int i = 0; i < N; i++) DPP_ADD(d[i], 0x111);
#pragma unroll
  for (int i = 0; i < N; i++) DPP_ADD(d[i], 0x112);
#pragma unroll
  for (int i = 0; i < N; i++) DPP_ADD(d[i], 0x114);
#pragma unroll
  for (int i = 0; i < N; i++) DPP_ADD(d[i], 0x118);
#pragma unroll
  for (int i = 0; i < N; i++) DPP_ADD(d[i], 0x142);
#pragma unroll
  for (int i = 0; i < N; i++) DPP_ADD(d[i], 0x143);
#pragma unroll
  for (int i = 0; i < N; i++)
    d[i] = __int_as_float(__builtin_amdgcn_readlane(__float_as_int(d[i]), 63));
}

// broadcast group-lane 31 to all lanes of each 32-lane group
__device__ __forceinline__ float swz31(float x) {
  return __int_as_float(__builtin_amdgcn_ds_swizzle(__float_as_int(x), 0x3E0));
}

// dual 32-lane reduce: 5 DPP stages put sum(0..31) in lane31, sum(32..63) in lane63,
// then swizzle-broadcast each half's sum to all its lanes.
template <int N>
__device__ __forceinline__ void dpp_reduce32(float (&d)[N]) {
#pragma unroll
  for (int i = 0; i < N; i++) DPP_ADD(d[i], 0x111);  // row_shr:1
#pragma unroll
  for (int i = 0; i < N; i++) DPP_ADD(d[i], 0x112);  // row_shr:2
#pragma unroll
  for (int i = 0; i < N; i++) DPP_ADD(d[i], 0x114);  // row_shr:4
#pragma unroll
  for (int i = 0; i < N; i++) DPP_ADD(d[i], 0x118);  // row_shr:8
#pragma unroll
  for (int i = 0; i < N; i++) DPP_ADD(d[i], 0x142);  // row_bcast:15
#pragma unroll
  for (int i = 0; i < N; i++) d[i] = swz31(d[i]);
}

// ---------------- fp32 -> bf16 cast
__global__ __launch_bounds__(256) void cast_hs(const float* __restrict__ src,
                                               ushort* __restrict__ dst) {
  int i = blockIdx.x * 256 + threadIdx.x;
  float4 v = ((const float4*)src)[i];
  ushort4 o = {f2bf(v.x), f2bf(v.y), f2bf(v.z), f2bf(v.w)};
  ((ushort4*)dst)[i] = o;
}

// ---------------- transpose+cast packed weights
__global__ __launch_bounds__(256) void tr_pack(const float* __restrict__ Wq,
                                               const float* __restrict__ Wk,
                                               const float* __restrict__ Wv,
                                               const float* __restrict__ Wg,
                                               ushort* __restrict__ Bt) {
  __shared__ float tile[32][33];
  int n0 = blockIdx.x * 32, k0 = blockIdx.y * 32;
  const float* src;
  int ld, nb;
  if (n0 < 512)       { src = Wq; ld = 512;  nb = n0; }
  else if (n0 < 1536) { src = Wk; ld = 1024; nb = n0 - 512; }
  else if (n0 < 3584) { src = Wv; ld = 2048; nb = n0 - 1536; }
  else                { src = Wg; ld = 1024; nb = n0 - 3584; }
  int tx = threadIdx.x & 31, ty = threadIdx.x >> 5;
#pragma unroll
  for (int i = 0; i < 4; i++)
    tile[ty + i * 8][tx] = src[(size_t)(k0 + ty + i * 8) * ld + nb + tx];
  __syncthreads();
#pragma unroll
  for (int i = 0; i < 4; i++)
    Bt[(size_t)(n0 + ty + i * 8) * 1024 + k0 + tx] = f2bf(tile[tx][ty + i * 8]);
}

__global__ __launch_bounds__(256) void tr_one(const float* __restrict__ W,
                                              ushort* __restrict__ Bt, int N) {
  __shared__ float tile[32][33];
  int n0 = blockIdx.x * 32, k0 = blockIdx.y * 32;
  int tx = threadIdx.x & 31, ty = threadIdx.x >> 5;
#pragma unroll
  for (int i = 0; i < 4; i++)
    tile[ty + i * 8][tx] = W[(size_t)(k0 + ty + i * 8) * N + n0 + tx];
  __syncthreads();
#pragma unroll
  for (int i = 0; i < 4; i++)
    Bt[(size_t)(n0 + ty + i * 8) * 1024 + k0 + tx] = f2bf(tile[tx][ty + i * 8]);
}

// ---------------- bf16 MFMA GEMM
#define LDP 40
__global__ __launch_bounds__(256) void gemm_bf16(const ushort* __restrict__ A,
                                                 const ushort* __restrict__ Bt,
                                                 float* __restrict__ C,
                                                 int K, int ldc) {
  __shared__ __align__(16) ushort As[128][LDP];
  __shared__ __align__(16) ushort Bs[128][LDP];
  const int tid = threadIdx.x;
  const int lane = tid & 63, wave = tid >> 6;
  const int wr = wave >> 1, wc = wave & 1;
  const int row0 = blockIdx.y * 128, col0 = blockIdx.x * 128;
  const int r = tid >> 1, hf = tid & 1;

  f32x4 acc[4][4];
#pragma unroll
  for (int i = 0; i < 4; i++)
#pragma unroll
    for (int j = 0; j < 4; j++) acc[i][j] = {0.f, 0.f, 0.f, 0.f};

  const int lrow = lane & 15, lk = (lane >> 4) * 8;

  for (int k0 = 0; k0 < K; k0 += 32) {
    const float4* pa = (const float4*)(A + (size_t)(row0 + r) * K + k0 + hf * 16);
    const float4* pb = (const float4*)(Bt + (size_t)(col0 + r) * K + k0 + hf * 16);
    float4 a0 = pa[0], a1 = pa[1];
    float4 b0 = pb[0], b1 = pb[1];
    __syncthreads();
    *(float4*)&As[r][hf * 16] = a0;
    *(float4*)&As[r][hf * 16 + 8] = a1;
    *(float4*)&Bs[r][hf * 16] = b0;
    *(float4*)&Bs[r][hf * 16 + 8] = b1;
    __syncthreads();
    bfx8 af[4], bf[4];
#pragma unroll
    for (int mf = 0; mf < 4; mf++)
      af[mf] = *(const bfx8*)&As[wr * 64 + mf * 16 + lrow][lk];
#pragma unroll
    for (int nf = 0; nf < 4; nf++)
      bf[nf] = *(const bfx8*)&Bs[wc * 64 + nf * 16 + lrow][lk];
#pragma unroll
    for (int mf = 0; mf < 4; mf++)
#pragma unroll
      for (int nf = 0; nf < 4; nf++)
        acc[mf][nf] = __builtin_amdgcn_mfma_f32_16x16x32_bf16(af[mf], bf[nf], acc[mf][nf], 0, 0, 0);
  }
  const int crow = (lane >> 4) * 4, ccol = lane & 15;
#pragma unroll
  for (int mf = 0; mf < 4; mf++)
#pragma unroll
    for (int nf = 0; nf < 4; nf++)
#pragma unroll
      for (int rr = 0; rr < 4; rr++)
        C[(size_t)(row0 + wr * 64 + mf * 16 + crow + rr) * ldc + col0 + wc * 64 + nf * 16 + ccol] =
            acc[mf][nf][rr];
}

// ---------------- beta / gamma tiny projections (gamma = exp(g))
__global__ __launch_bounds__(256) void proj_bg(const float* __restrict__ hs,
                                               const float* __restrict__ Wb,
                                               const float* __restrict__ Wa,
                                               const float* __restrict__ A_log,
                                               const float* __restrict__ dt_bias,
                                               float* __restrict__ beta,
                                               float* __restrict__ g) {
  int row = blockIdx.x;
  int lane = threadIdx.x & 63;
  int wave = threadIdx.x >> 6;
  const float* x = hs + (size_t)row * HID;
  for (int out = wave; out < 12; out += 4) {
    float sum = 0.f;
    if (out < 8) {
      for (int k = lane; k < HID; k += 64) sum = fmaf(x[k], Wb[(size_t)k * 8 + out], sum);
    } else {
      int c = out - 8;
      for (int k = lane; k < HID; k += 64) sum = fmaf(x[k], Wa[(size_t)k * 4 + c], sum);
    }
    sum = wave_sum(sum);
    if (lane == 0) {
      if (out < 8) {
        beta[(size_t)row * 8 + out] = 2.f / (1.f + expf(-sum));
      } else {
        int h = out - 8;
        float xx = sum + dt_bias[h];
        float sp = (xx > 20.f) ? xx : log1pf(expf(xx));
        g[(size_t)row * 4 + h] = expf(-expf(A_log[h]) * sp);  // gamma
      }
    }
  }
}

// ---------------- conv+SiLU+l2norm for q -> pair-interleaved layout
__global__ __launch_bounds__(128) void conv_q(const float* __restrict__ x, int ldx,
                                              const float* __restrict__ w,
                                              float* __restrict__ y, int T) {
  int rb = blockIdx.x;
  int h = rb % 4;
  int bt = rb / 4;
  int t = bt % T;
  int b = bt / T;
  int d = threadIdx.x;
  int c = h * 128 + d;
  const float* wc = w + (size_t)c * KSZ;
  float acc = 0.f;
#pragma unroll
  for (int i = 0; i < KSZ; i++) {
    int tt = t - (KSZ - 1) + i;
    if (tt >= 0) acc = fmaf(x[(size_t)(b * T + tt) * ldx + c], wc[i], acc);
  }
  float val = acc / (1.f + expf(-acc));
  float ss = wave_sum(val * val);
  __shared__ float sred[2];
  if ((threadIdx.x & 63) == 0) sred[threadIdx.x >> 6] = ss;
  __syncthreads();
  val *= rsqrtf(sred[0] + sred[1] + 1e-6f);
  y[((size_t)(b * 512 + (t >> 1)) * 4 + h) * 256 + (d >> 1) * 4 + (d & 1) + (t & 1) * 2] = val;
}

// ---------------- conv+SiLU+l2norm for k -> copy-interleaved layout
__global__ __launch_bounds__(128) void conv_k(const float* __restrict__ x, int ldx,
                                              const float* __restrict__ w,
                                              float* __restrict__ y, int T) {
  int rb = blockIdx.x;
  int gi = rb % 8;  // i*4 + h
  int bt = rb / 8;
  int t = bt % T;
  int b = bt / T;
  int i = gi >> 2, h = gi & 3;
  int d = threadIdx.x;
  int c = i * 512 + h * 128 + d;
  const float* wc = w + (size_t)c * KSZ;
  float acc = 0.f;
#pragma unroll
  for (int kk = 0; kk < KSZ; kk++) {
    int tt = t - (KSZ - 1) + kk;
    if (tt >= 0) acc = fmaf(x[(size_t)(b * T + tt) * ldx + c], wc[kk], acc);
  }
  float val = acc / (1.f + expf(-acc));
  float ss = wave_sum(val * val);
  __shared__ float sred[2];
  if ((threadIdx.x & 63) == 0) sred[threadIdx.x >> 6] = ss;
  __syncthreads();
  val *= rsqrtf(sred[0] + sred[1] + 1e-6f);
  y[((size_t)(b * T + t) * 4 + h) * 256 + (d >> 1) * 4 + (d & 1) + i * 2] = val;
}

// ---------------- conv+SiLU for v -> pair-major layout
__global__ __launch_bounds__(256) void conv_v(const float* __restrict__ x, int ldx,
                                              const float* __restrict__ w,
                                              float* __restrict__ y, int T) {
  int rb = blockIdx.x;
  int gi = rb % 8;  // i*4 + h
  int bt = rb / 8;
  int t = bt % T;
  int b = bt / T;
  int i = gi >> 2, h = gi & 3;
  int d = threadIdx.x;
  int c = i * 1024 + h * 256 + d;
  const float* wc = w + (size_t)c * KSZ;
  float acc = 0.f;
#pragma unroll
  for (int kk = 0; kk < KSZ; kk++) {
    int tt = t - (KSZ - 1) + kk;
    if (tt >= 0) acc = fmaf(x[(size_t)(b * T + tt) * ldx + c], wc[kk], acc);
  }
  float val = acc / (1.f + expf(-acc));
  y[((size_t)(b * 512 + (t >> 1)) * 4 + h) * 1024 + d * 4 + (t & 1) * 2 + i] = val;
}

// ---------------- 2-step coefficient records (24 floats per (b,tp,h))
__global__ __launch_bounds__(256) void cross_dots2(const float* __restrict__ kbuf2,
                                                   const float* __restrict__ qbuf2,
                                                   const float* __restrict__ beta,
                                                   const float* __restrict__ gam,
                                                   float* __restrict__ rec) {
  int idx = blockIdx.x * 4 + (threadIdx.x >> 6);  // (b*512+tp)*4 + h
  int lane = threadIdx.x & 63;
  int h = idx & 3, tp = (idx >> 2) & 511, b = idx >> 11;
  int t = 2 * tp;
  const float4 kA = *(const float4*)&kbuf2[((size_t)(b * 1024 + t) * 4 + h) * 256 + lane * 4];
  const float4 kB = *(const float4*)&kbuf2[((size_t)(b * 1024 + t + 1) * 4 + h) * 256 + lane * 4];
  const float4 qv = *(const float4*)&qbuf2[(size_t)idx * 256 + lane * 4];
  float d[12];
  d[0] = kA.z * kA.x + kA.w * kA.y;   // d10
  d[1] = kB.x * kA.x + kB.y * kA.y;   // d20
  d[2] = kB.x * kA.z + kB.y * kA.w;   // d21
  d[3] = kB.z * kA.x + kB.w * kA.y;   // d30
  d[4] = kB.z * kA.z + kB.w * kA.w;   // d31
  d[5] = kB.z * kB.x + kB.w * kB.y;   // d32
  d[6] = qv.x * kA.x + qv.y * kA.y;   // e00
  d[7] = qv.x * kA.z + qv.y * kA.w;   // e01
  d[8] = qv.z * kA.x + qv.w * kA.y;   // e10
  d[9] = qv.z * kA.z + qv.w * kA.w;   // e11
  d[10] = qv.z * kB.x + qv.w * kB.y;  // e12
  d[11] = qv.z * kB.z + qv.w * kB.w;  // e13
  dpp_reduce(d);
  int bt = b * 1024 + t;
  float b0 = beta[(size_t)(bt * 2 + 0) * 4 + h];
  float b1 = beta[(size_t)(bt * 2 + 1) * 4 + h];
  float b2 = beta[(size_t)(bt * 2 + 2) * 4 + h];
  float b3 = beta[(size_t)(bt * 2 + 3) * 4 + h];
  float gt = gam[(size_t)bt * 4 + h];
  float gt1 = gam[(size_t)(bt + 1) * 4 + h];
  if (lane == 0) {
    float G2 = gt * gt1;
    float4* rp = (float4*)&rec[(size_t)idx * 24];
    rp[0] = {b0 * gt, b1 * gt, b1 * d[0], gt};
    rp[1] = {b2 * G2, b2 * gt1 * d[1], b2 * gt1 * d[2], gt1};
    rp[2] = {b3 * G2, b3 * gt1 * d[3], b3 * gt1 * d[4], b3 * d[5]};
    rp[3] = {d[6], d[7], G2, b0};
    rp[4] = {gt1 * d[8], gt1 * d[9], d[10], d[11]};
    rp[5] = {b1, b2, b3, 0.f};
  }
}

// ---------------- 2-step QUAD-COLUMN scan: one wave serves 4 DV-columns via TWO
// independent column-streams (state chains) sharing all k/q/rec loads.
// Lanes 0-31 / 32-63 split columns within a stream (as R15); stream 2 = cols +2.
// The 12 r-dot reductions interleave in ONE DPP+swizzle session -> the two
// streams' chains supply intra-wave ILP that replaces the missing 2nd wave/SIMD
// (R15's regression root cause). Per-column VALU ~57 instr vs R14's 225.
__global__ __launch_bounds__(64, 1) void scan2(const float4* __restrict__ kb,
                                               const float4* __restrict__ qb,
                                               const float4* __restrict__ vb,
                                               const float4* __restrict__ rb,
                                               float* __restrict__ o) {
  const int lane = threadIdx.x & 63;
  const int l32 = lane & 31;
  const int bh = blockIdx.x & 7;   // XCD-local
  const int quad = blockIdx.x >> 3;  // 0..63
  const int b = bh >> 2, h = bh & 3;
  const int col = quad * 4 + (lane >> 5);  // stream1 col; stream2 = col+2

  const float4* kp = kb + ((size_t)(b * 1024) * 4 + h) * 64 + l32 * 2 + 128;
  const float4* qp = qb + ((size_t)(b * 512) * 4 + h) * 64 + l32 * 2;
  const float4* vp = vb + ((size_t)(b * 512) * 4 + h) * 256 + col;
  const float4* rp = rb + ((size_t)(b * 512) * 4 + h) * 6;
  float* op = o + (size_t)(b * 1024) * NTOT + h * 256 + col;

  // stream states: 4 floats/lane over DK=128 per column
  float s0 = 0.f, s1 = 0.f, s2 = 0.f, s3 = 0.f;   // stream 1
  float u0 = 0.f, u1 = 0.f, u2 = 0.f, u3 = 0.f;   // stream 2

  float4 AkA1, AkA2, AkB1, AkB2, Aqv1, Aqv2, Avv, Aww, AR0, AR1, AR2, AR3, AR4, AR5;
  float4 BkA1, BkA2, BkB1, BkB2, Bqv1, Bqv2, Bvv, Bww, BR0, BR1, BR2, BR3, BR4, BR5;

#define LOADQ(P) { \
    P##kA1 = kp[-128]; P##kA2 = kp[-127]; \
    P##kB1 = kp[128];  P##kB2 = kp[129]; \
    P##qv1 = qp[0];    P##qv2 = qp[1]; \
    P##vv  = vp[0];    P##ww  = vp[2]; \
    P##R0 = rp[0]; P##R1 = rp[1]; P##R2 = rp[2]; \
    P##R3 = rp[3]; P##R4 = rp[4]; P##R5 = rp[5]; \
    kp += 512; qp += 256; vp += 1024; rp += 24; }

#define STEPQ(P) { \
    float r[12]; \
    r[0]  = P##kA1.x * s0 + P##kA1.y * s1 + P##kA2.x * s2 + P##kA2.y * s3; \
    r[1]  = P##kA1.z * s0 + P##kA1.w * s1 + P##kA2.z * s2 + P##kA2.w * s3; \
    r[2]  = P##kB1.x * s0 + P##kB1.y * s1 + P##kB2.x * s2 + P##kB2.y * s3; \
    r[3]  = P##kB1.z * s0 + P##kB1.w * s1 + P##kB2.z * s2 + P##kB2.w * s3; \
    r[4]  = P##qv1.x * s0 + P##qv1.y * s1 + P##qv2.x * s2 + P##qv2.y * s3; \
    r[5]  = P##qv1.z * s0 + P##qv1.w * s1 + P##qv2.z * s2 + P##qv2.w * s3; \
    r[6]  = P##kA1.x * u0 + P##kA1.y * u1 + P##kA2.x * u2 + P##kA2.y * u3; \
    r[7]  = P##kA1.z * u0 + P##kA1.w * u1 + P##kA2.z * u2 + P##kA2.w * u3; \
    r[8]  = P##kB1.x * u0 + P##kB1.y * u1 + P##kB2.x * u2 + P##kB2.y * u3; \
    r[9]  = P##kB1.z * u0 + P##kB1.w * u1 + P##kB2.z * u2 + P##kB2.w * u3; \
    r[10] = P##qv1.x * u0 + P##qv1.y * u1 + P##qv2.x * u2 + P##qv2.y * u3; \
    r[11] = P##qv1.z * u0 + P##qv1.w * u1 + P##qv2.z * u2 + P##qv2.w * u3; \
    dpp_reduce32(r); \
    /* stream 1 */ \
    float c0 = fmaf(-P##R0.x, r[0], P##R3.w * P##vv.x); \
    float c1 = fmaf(-P##R0.z, c0, fmaf(-P##R0.y, r[1], P##R5.x * P##vv.y)); \
    float c2 = fmaf(-P##R1.z, c1, fmaf(-P##R1.y, c0, fmaf(-P##R1.x, r[2], P##R5.y * P##vv.z))); \
    float c3 = fmaf(-P##R2.w, c2, fmaf(-P##R2.z, c1, fmaf(-P##R2.y, c0, \
               fmaf(-P##R2.x, r[3], P##R5.z * P##vv.w)))); \
    float ot  = fmaf(P##R3.y, c1, fmaf(P##R3.x, c0, P##R0.w * r[4])); \
    float ot1 = fmaf(P##R4.w, c3, fmaf(P##R4.z, c2, fmaf(P##R4.y, c1, \
                fmaf(P##R4.x, c0, P##R3.z * r[5])))); \
    /* stream 2 */ \
    float e0 = fmaf(-P##R0.x, r[6], P##R3.w * P##ww.x); \
    float e1 = fmaf(-P##R0.z, e0, fmaf(-P##R0.y, r[7], P##R5.x * P##ww.y)); \
    float e2 = fmaf(-P##R1.z, e1, fmaf(-P##R1.y, e0, fmaf(-P##R1.x, r[8], P##R5.y * P##ww.z))); \
    float e3 = fmaf(-P##R2.w, e2, fmaf(-P##R2.z, e1, fmaf(-P##R2.y, e0, \
               fmaf(-P##R2.x, r[9], P##R5.z * P##ww.w)))); \
    float pt  = fmaf(P##R3.y, e1, fmaf(P##R3.x, e0, P##R0.w * r[10])); \
    float pt1 = fmaf(P##R4.w, e3, fmaf(P##R4.z, e2, fmaf(P##R4.y, e1, \
                fmaf(P##R4.x, e0, P##R3.z * r[11])))); \
    float g0 = P##R1.w * c0, g1 = P##R1.w * c1; \
    float f0 = P##R1.w * e0, f1 = P##R1.w * e1; \
    float G2 = P##R3.z; \
    s0 = fmaf(c3, P##kB1.z, fmaf(c2, P##kB1.x, fmaf(g1, P##kA1.z, fmaf(g0, P##kA1.x, G2 * s0)))); \
    s1 = fmaf(c3, P##kB1.w, fmaf(c2, P##kB1.y, fmaf(g1, P##kA1.w, fmaf(g0, P##kA1.y, G2 * s1)))); \
    s2 = fmaf(c3, P##kB2.z, fmaf(c2, P##kB2.x, fmaf(g1, P##kA2.z, fmaf(g0, P##kA2.x, G2 * s2)))); \
    s3 = fmaf(c3, P##kB2.w, fmaf(c2, P##kB2.y, fmaf(g1, P##kA2.w, fmaf(g0, P##kA2.y, G2 * s3)))); \
    u0 = fmaf(e3, P##kB1.z, fmaf(e2, P##kB1.x, fmaf(f1, P##kA1.z, fmaf(f0, P##kA1.x, G2 * u0)))); \
    u1 = fmaf(e3, P##kB1.w, fmaf(e2, P##kB1.y, fmaf(f1, P##kA1.w, fmaf(f0, P##kA1.y, G2 * u1)))); \
    u2 = fmaf(e3, P##kB2.z, fmaf(e2, P##kB2.x, fmaf(f1, P##kA2.z, fmaf(f0, P##kA2.x, G2 * u2)))); \
    u3 = fmaf(e3, P##kB2.w, fmaf(e2, P##kB2.y, fmaf(f1, P##kA2.w, fmaf(f0, P##kA2.y, G2 * u3)))); \
    if (l32 == 0) { op[0] = ot; op[NTOT] = ot1; op[2] = pt; op[2 + NTOT] = pt1; } \
    op += 2 * NTOT; }

  LOADQ(A)
  LOADQ(B)
  for (int it = 0; it < 255; ++it) {
    STEPQ(A) LOADQ(A)
    STEPQ(B) LOADQ(B)
  }
  STEPQ(A)
  STEPQ(B)
#undef LOADQ
#undef STEPQ
}

// ---------------- RMSNorm(o) * w * SiLU(gate); writes dense bf16 [M][1024]
__global__ __launch_bounds__(256) void post_norm_gate(const float* __restrict__ o,
                                                      const float* __restrict__ gate,
                                                      const float* __restrict__ w,
                                                      ushort* __restrict__ obf) {
  int rb = blockIdx.x;
  int bt = rb >> 2, h = rb & 3;
  int tid = threadIdx.x;
  size_t ob = (size_t)bt * NTOT + h * 256 + tid;
  float ov = o[ob];
  float ss = wave_sum(ov * ov);
  __shared__ float sred[4];
  if ((tid & 63) == 0) sred[tid >> 6] = ss;
  __syncthreads();
  float tot = sred[0] + sred[1] + sred[2] + sred[3];
  float rms = rsqrtf(tot * (1.f / 256.f) + 1e-5f);
  float gt = gate[(size_t)bt * NTOT + h * 256 + tid];
  float val = ov * rms * w[tid] * (gt / (1.f + expf(-gt)));
  obf[(size_t)bt * HID + h * 256 + tid] = f2bf(val);
}

extern "C" void kernel_launch(void* const* d_in, const int* in_sizes, int n_in,
                              void* d_out, int out_size, void* d_ws, size_t ws_size,
                              hipStream_t stream) {
  const float* hs      = (const float*)d_in[0];
  const float* Wq      = (const float*)d_in[1];
  const float* Wk      = (const float*)d_in[2];
  const float* Wv      = (const float*)d_in[3];
  const float* Wb      = (const float*)d_in[4];
  const float* Wa      = (const float*)d_in[5];
  const float* Wg      = (const float*)d_in[6];
  const float* Wo      = (const float*)d_in[7];
  const float* A_log   = (const float*)d_in[8];
  const float* dt_bias = (const float*)d_in[9];
  const float* wq_conv = (const float*)d_in[10];
  const float* wk_conv = (const float*)d_in[11];
  const float* wv_conv = (const float*)d_in[12];
  const float* o_w     = (const float*)d_in[13];
  float* out = (float*)d_out;

  const int B = 2, T = 1024, M = B * T;

  float* ws    = (float*)d_ws;
  float* qkvg  = ws;                          // M*4608 fp32; cols 0..1023 get o; 3584+ gate
  float* kbuf  = qkvg + (size_t)M * NTOT;     // M*1024 (k interleaved)
  float* vbuf  = kbuf + (size_t)M * 1024;     // M*2048 (v pair-major)
  float* betab = vbuf + (size_t)M * 2048;     // M*8
  float* gb    = betab + (size_t)M * 8;       // M*4 (gamma)
  float* recb  = gb + (size_t)M * 4;          // 4096*24 floats
  float* qbuf  = out;                         // M*512 scratch (q pair-interleaved)

  // time-disjoint bf16 aliases in kbuf/vbuf regions:
  ushort* bqkvgT = (ushort*)kbuf;
  ushort* hsb    = (ushort*)(vbuf + (size_t)524288);  // vbuf + 2MB
  ushort* woT = (ushort*)kbuf;
  ushort* obf = (ushort*)vbuf;

  // casts + projections
  cast_hs<<<(M * HID / 4) / 256, 256, 0, stream>>>(hs, hsb);
  tr_pack<<<dim3(NTOT / 32, HID / 32), 256, 0, stream>>>(Wq, Wk, Wv, Wg, bqkvgT);
  gemm_bf16<<<dim3(NTOT / 128, M / 128), 256, 0, stream>>>(hsb, bqkvgT, qkvg, HID, NTOT);
  proj_bg<<<M, 256, 0, stream>>>(hs, Wb, Wa, A_log, dt_bias, betab, gb);
  // conv + SiLU (+ l2norm q,k) into scan-friendly layouts
  conv_q<<<M * 4, 128, 0, stream>>>(qkvg + 0, NTOT, wq_conv, qbuf, T);
  conv_k<<<M * 8, 128, 0, stream>>>(qkvg + 512, NTOT, wk_conv, kbuf, T);
  conv_v<<<M * 8, 256, 0, stream>>>(qkvg + 1536, NTOT, wv_conv, vbuf, T);
  // 2-step coefficient records
  cross_dots2<<<M * H / 8, 256, 0, stream>>>(kbuf, qbuf, betab, gb, recb);
  // quad-column batched scan -> o into qkvg cols 0..1023 (512 waves, 64-thr blocks)
  scan2<<<512, 64, 0, stream>>>((const float4*)kbuf, (const float4*)qbuf,
                                (const float4*)vbuf, (const float4*)recb, qkvg);
  // epilogue + output projection
  post_norm_gate<<<M * H, 256, 0, stream>>>(qkvg, qkvg + 3584, o_w, obf);
  tr_one<<<dim3(HID / 32, HID / 32), 256, 0, stream>>>(Wo, woT, HID);
  gemm_bf16<<<dim3(HID / 128, M / 128), 256, 0, stream>>>(obf, woT, out, HID, HID);
}

// Round 17
// 428.024 us; speedup vs baseline: 1.2359x; 1.2359x over previous
//
#include <hip/hip_runtime.h>
#include <cstdint>
#include <cstddef>

#define H 4
#define DK 128
#define DV 256
#define NH 2
#define HID 1024
#define KSZ 4
#define NTOT 4608  // packed projection width: 512 q | 1024 k | 2048 v | 1024 g

typedef __bf16 bfx8 __attribute__((ext_vector_type(8)));
typedef float f32x4 __attribute__((ext_vector_type(4)));

__device__ __forceinline__ float wave_sum(float x) {
#pragma unroll
  for (int off = 1; off < 64; off <<= 1) x += __shfl_xor(x, off, 64);
  return x;
}

__device__ __forceinline__ ushort f2bf(float x) {
  uint u = __float_as_uint(x);
  return (ushort)((u + 0x7fffu + ((u >> 16) & 1u)) >> 16);
}

#define DPP_ADD(x, ctrl) \
  x += __int_as_float(__builtin_amdgcn_update_dpp(0, __float_as_int(x), ctrl, 0xf, 0xf, true))

// N independent full-wave64 sums (6-stage); results uniform via readlane(63)
template <int N>
__device__ __forceinline__ void dpp_reduce(float (&d)[N]) {
#pragma unroll
  for (int i = 0; i < N; i++) DPP_ADD(d[i], 0x111);
#pragma unroll
  for (int i = 0; i < N; i++) DPP_ADD(d[i], 0x112);
#pragma unroll
  for (int i = 0; i < N; i++) DPP_ADD(d[i], 0x114);
#pragma unroll
  for (int i = 0; i < N; i++) DPP_ADD(d[i], 0x118);
#pragma unroll
  for (int i = 0; i < N; i++) DPP_ADD(d[i], 0x142);
#pragma unroll
  for (int i = 0; i < N; i++) DPP_ADD(d[i], 0x143);
#pragma unroll
  for (int i = 0; i < N; i++)
    d[i] = __int_as_float(__builtin_amdgcn_readlane(__float_as_int(d[i]), 63));
}

// ---------------- fp32 -> bf16 cast
__global__ __launch_bounds__(256) void cast_hs(const float* __restrict__ src,
                                               ushort* __restrict__ dst) {
  int i = blockIdx.x * 256 + threadIdx.x;
  float4 v = ((const float4*)src)[i];
  ushort4 o = {f2bf(v.x), f2bf(v.y), f2bf(v.z), f2bf(v.w)};
  ((ushort4*)dst)[i] = o;
}

// ---------------- transpose+cast packed weights
__global__ __launch_bounds__(256) void tr_pack(const float* __restrict__ Wq,
                                               const float* __restrict__ Wk,
                                               const float* __restrict__ Wv,
                                               const float* __restrict__ Wg,
                                               ushort* __restrict__ Bt) {
  __shared__ float tile[32][33];
  int n0 = blockIdx.x * 32, k0 = blockIdx.y * 32;
  const float* src;
  int ld, nb;
  if (n0 < 512)       { src = Wq; ld = 512;  nb = n0; }
  else if (n0 < 1536) { src = Wk; ld = 1024; nb = n0 - 512; }
  else if (n0 < 3584) { src = Wv; ld = 2048; nb = n0 - 1536; }
  else                { src = Wg; ld = 1024; nb = n0 - 3584; }
  int tx = threadIdx.x & 31, ty = threadIdx.x >> 5;
#pragma unroll
  for (int i = 0; i < 4; i++)
    tile[ty + i * 8][tx] = src[(size_t)(k0 + ty + i * 8) * ld + nb + tx];
  __syncthreads();
#pragma unroll
  for (int i = 0; i < 4; i++)
    Bt[(size_t)(n0 + ty + i * 8) * 1024 + k0 + tx] = f2bf(tile[tx][ty + i * 8]);
}

__global__ __launch_bounds__(256) void tr_one(const float* __restrict__ W,
                                              ushort* __restrict__ Bt, int N) {
  __shared__ float tile[32][33];
  int n0 = blockIdx.x * 32, k0 = blockIdx.y * 32;
  int tx = threadIdx.x & 31, ty = threadIdx.x >> 5;
#pragma unroll
  for (int i = 0; i < 4; i++)
    tile[ty + i * 8][tx] = W[(size_t)(k0 + ty + i * 8) * N + n0 + tx];
  __syncthreads();
#pragma unroll
  for (int i = 0; i < 4; i++)
    Bt[(size_t)(n0 + ty + i * 8) * 1024 + k0 + tx] = f2bf(tile[tx][ty + i * 8]);
}

// ---------------- bf16 MFMA GEMM
#define LDP 40
__global__ __launch_bounds__(256) void gemm_bf16(const ushort* __restrict__ A,
                                                 const ushort* __restrict__ Bt,
                                                 float* __restrict__ C,
                                                 int K, int ldc) {
  __shared__ __align__(16) ushort As[128][LDP];
  __shared__ __align__(16) ushort Bs[128][LDP];
  const int tid = threadIdx.x;
  const int lane = tid & 63, wave = tid >> 6;
  const int wr = wave >> 1, wc = wave & 1;
  const int row0 = blockIdx.y * 128, col0 = blockIdx.x * 128;
  const int r = tid >> 1, hf = tid & 1;

  f32x4 acc[4][4];
#pragma unroll
  for (int i = 0; i < 4; i++)
#pragma unroll
    for (int j = 0; j < 4; j++) acc[i][j] = {0.f, 0.f, 0.f, 0.f};

  const int lrow = lane & 15, lk = (lane >> 4) * 8;

  for (int k0 = 0; k0 < K; k0 += 32) {
    const float4* pa = (const float4*)(A + (size_t)(row0 + r) * K + k0 + hf * 16);
    const float4* pb = (const float4*)(Bt + (size_t)(col0 + r) * K + k0 + hf * 16);
    float4 a0 = pa[0], a1 = pa[1];
    float4 b0 = pb[0], b1 = pb[1];
    __syncthreads();
    *(float4*)&As[r][hf * 16] = a0;
    *(float4*)&As[r][hf * 16 + 8] = a1;
    *(float4*)&Bs[r][hf * 16] = b0;
    *(float4*)&Bs[r][hf * 16 + 8] = b1;
    __syncthreads();
    bfx8 af[4], bf[4];
#pragma unroll
    for (int mf = 0; mf < 4; mf++)
      af[mf] = *(const bfx8*)&As[wr * 64 + mf * 16 + lrow][lk];
#pragma unroll
    for (int nf = 0; nf < 4; nf++)
      bf[nf] = *(const bfx8*)&Bs[wc * 64 + nf * 16 + lrow][lk];
#pragma unroll
    for (int mf = 0; mf < 4; mf++)
#pragma unroll
      for (int nf = 0; nf < 4; nf++)
        acc[mf][nf] = __builtin_amdgcn_mfma_f32_16x16x32_bf16(af[mf], bf[nf], acc[mf][nf], 0, 0, 0);
  }
  const int crow = (lane >> 4) * 4, ccol = lane & 15;
#pragma unroll
  for (int mf = 0; mf < 4; mf++)
#pragma unroll
    for (int nf = 0; nf < 4; nf++)
#pragma unroll
      for (int rr = 0; rr < 4; rr++)
        C[(size_t)(row0 + wr * 64 + mf * 16 + crow + rr) * ldc + col0 + wc * 64 + nf * 16 + ccol] =
            acc[mf][nf][rr];
}

// ---------------- beta / gamma tiny projections (gamma = exp(g))
__global__ __launch_bounds__(256) void proj_bg(const float* __restrict__ hs,
                                               const float* __restrict__ Wb,
                                               const float* __restrict__ Wa,
                                               const float* __restrict__ A_log,
                                               const float* __restrict__ dt_bias,
                                               float* __restrict__ beta,
                                               float* __restrict__ g) {
  int row = blockIdx.x;
  int lane = threadIdx.x & 63;
  int wave = threadIdx.x >> 6;
  const float* x = hs + (size_t)row * HID;
  for (int out = wave; out < 12; out += 4) {
    float sum = 0.f;
    if (out < 8) {
      for (int k = lane; k < HID; k += 64) sum = fmaf(x[k], Wb[(size_t)k * 8 + out], sum);
    } else {
      int c = out - 8;
      for (int k = lane; k < HID; k += 64) sum = fmaf(x[k], Wa[(size_t)k * 4 + c], sum);
    }
    sum = wave_sum(sum);
    if (lane == 0) {
      if (out < 8) {
        beta[(size_t)row * 8 + out] = 2.f / (1.f + expf(-sum));
      } else {
        int h = out - 8;
        float xx = sum + dt_bias[h];
        float sp = (xx > 20.f) ? xx : log1pf(expf(xx));
        g[(size_t)row * 4 + h] = expf(-expf(A_log[h]) * sp);  // gamma
      }
    }
  }
}

// ---------------- conv+SiLU+l2norm for q -> pair-interleaved layout
__global__ __launch_bounds__(128) void conv_q(const float* __restrict__ x, int ldx,
                                              const float* __restrict__ w,
                                              float* __restrict__ y, int T) {
  int rb = blockIdx.x;
  int h = rb % 4;
  int bt = rb / 4;
  int t = bt % T;
  int b = bt / T;
  int d = threadIdx.x;
  int c = h * 128 + d;
  const float* wc = w + (size_t)c * KSZ;
  float acc = 0.f;
#pragma unroll
  for (int i = 0; i < KSZ; i++) {
    int tt = t - (KSZ - 1) + i;
    if (tt >= 0) acc = fmaf(x[(size_t)(b * T + tt) * ldx + c], wc[i], acc);
  }
  float val = acc / (1.f + expf(-acc));
  float ss = wave_sum(val * val);
  __shared__ float sred[2];
  if ((threadIdx.x & 63) == 0) sred[threadIdx.x >> 6] = ss;
  __syncthreads();
  val *= rsqrtf(sred[0] + sred[1] + 1e-6f);
  y[((size_t)(b * 512 + (t >> 1)) * 4 + h) * 256 + (d >> 1) * 4 + (d & 1) + (t & 1) * 2] = val;
}

// ---------------- conv+SiLU+l2norm for k -> copy-interleaved layout
__global__ __launch_bounds__(128) void conv_k(const float* __restrict__ x, int ldx,
                                              const float* __restrict__ w,
                                              float* __restrict__ y, int T) {
  int rb = blockIdx.x;
  int gi = rb % 8;  // i*4 + h
  int bt = rb / 8;
  int t = bt % T;
  int b = bt / T;
  int i = gi >> 2, h = gi & 3;
  int d = threadIdx.x;
  int c = i * 512 + h * 128 + d;
  const float* wc = w + (size_t)c * KSZ;
  float acc = 0.f;
#pragma unroll
  for (int kk = 0; kk < KSZ; kk++) {
    int tt = t - (KSZ - 1) + kk;
    if (tt >= 0) acc = fmaf(x[(size_t)(b * T + tt) * ldx + c], wc[kk], acc);
  }
  float val = acc / (1.f + expf(-acc));
  float ss = wave_sum(val * val);
  __shared__ float sred[2];
  if ((threadIdx.x & 63) == 0) sred[threadIdx.x >> 6] = ss;
  __syncthreads();
  val *= rsqrtf(sred[0] + sred[1] + 1e-6f);
  y[((size_t)(b * T + t) * 4 + h) * 256 + (d >> 1) * 4 + (d & 1) + i * 2] = val;
}

// ---------------- conv+SiLU for v -> pair-major layout
__global__ __launch_bounds__(256) void conv_v(const float* __restrict__ x, int ldx,
                                              const float* __restrict__ w,
                                              float* __restrict__ y, int T) {
  int rb = blockIdx.x;
  int gi = rb % 8;  // i*4 + h
  int bt = rb / 8;
  int t = bt % T;
  int b = bt / T;
  int i = gi >> 2, h = gi & 3;
  int d = threadIdx.x;
  int c = i * 1024 + h * 256 + d;
  const float* wc = w + (size_t)c * KSZ;
  float acc = 0.f;
#pragma unroll
  for (int kk = 0; kk < KSZ; kk++) {
    int tt = t - (KSZ - 1) + kk;
    if (tt >= 0) acc = fmaf(x[(size_t)(b * T + tt) * ldx + c], wc[kk], acc);
  }
  float val = acc / (1.f + expf(-acc));
  y[((size_t)(b * 512 + (t >> 1)) * 4 + h) * 1024 + d * 4 + (t & 1) * 2 + i] = val;
}

// ---------------- 2-step coefficient records (24 floats per (b,tp,h))
__global__ __launch_bounds__(256) void cross_dots2(const float* __restrict__ kbuf2,
                                                   const float* __restrict__ qbuf2,
                                                   const float* __restrict__ beta,
                                                   const float* __restrict__ gam,
                                                   float* __restrict__ rec) {
  int idx = blockIdx.x * 4 + (threadIdx.x >> 6);  // (b*512+tp)*4 + h
  int lane = threadIdx.x & 63;
  int h = idx & 3, tp = (idx >> 2) & 511, b = idx >> 11;
  int t = 2 * tp;
  const float4 kA = *(const float4*)&kbuf2[((size_t)(b * 1024 + t) * 4 + h) * 256 + lane * 4];
  const float4 kB = *(const float4*)&kbuf2[((size_t)(b * 1024 + t + 1) * 4 + h) * 256 + lane * 4];
  const float4 qv = *(const float4*)&qbuf2[(size_t)idx * 256 + lane * 4];
  float d[12];
  d[0] = kA.z * kA.x + kA.w * kA.y;   // d10
  d[1] = kB.x * kA.x + kB.y * kA.y;   // d20
  d[2] = kB.x * kA.z + kB.y * kA.w;   // d21
  d[3] = kB.z * kA.x + kB.w * kA.y;   // d30
  d[4] = kB.z * kA.z + kB.w * kA.w;   // d31
  d[5] = kB.z * kB.x + kB.w * kB.y;   // d32
  d[6] = qv.x * kA.x + qv.y * kA.y;   // e00
  d[7] = qv.x * kA.z + qv.y * kA.w;   // e01
  d[8] = qv.z * kA.x + qv.w * kA.y;   // e10
  d[9] = qv.z * kA.z + qv.w * kA.w;   // e11
  d[10] = qv.z * kB.x + qv.w * kB.y;  // e12
  d[11] = qv.z * kB.z + qv.w * kB.w;  // e13
  dpp_reduce(d);
  int bt = b * 1024 + t;
  float b0 = beta[(size_t)(bt * 2 + 0) * 4 + h];
  float b1 = beta[(size_t)(bt * 2 + 1) * 4 + h];
  float b2 = beta[(size_t)(bt * 2 + 2) * 4 + h];
  float b3 = beta[(size_t)(bt * 2 + 3) * 4 + h];
  float gt = gam[(size_t)bt * 4 + h];
  float gt1 = gam[(size_t)(bt + 1) * 4 + h];
  if (lane == 0) {
    float G2 = gt * gt1;
    float4* rp = (float4*)&rec[(size_t)idx * 24];
    rp[0] = {b0 * gt, b1 * gt, b1 * d[0], gt};
    rp[1] = {b2 * G2, b2 * gt1 * d[1], b2 * gt1 * d[2], gt1};
    rp[2] = {b3 * G2, b3 * gt1 * d[3], b3 * gt1 * d[4], b3 * d[5]};
    rp[3] = {d[6], d[7], G2, b0};
    rp[4] = {gt1 * d[8], gt1 * d[9], d[10], d[11]};
    rp[5] = {b1, b2, b3, 0.f};
  }
}

// ---------------- 2-step batched gated-delta scan, one wave per (b,h,dv-column)
// R14 configuration (best measured: 264 us, VALUBusy 73%): plain-C++ loads,
// rolling-pointer addressing with constant offsets, depth-2 named-slot FIFO,
// 512 blocks x 256 thr = 2048 waves = 2 waves/SIMD (TLP covers chain latency).
// R15 (2 col/wave) and R16 (4 col/wave) both regressed: instruction sharing
// cannot pay for the lost wave-level parallelism once columns are exhausted.
__global__ __launch_bounds__(256, 2) void scan2(const float4* __restrict__ kb,
                                                const float4* __restrict__ qb,
                                                const float4* __restrict__ vb,
                                                const float4* __restrict__ rb,
                                                float* __restrict__ o) {
  const int lane = threadIdx.x & 63;
  const int wave = __builtin_amdgcn_readfirstlane(threadIdx.x >> 6);
  const int bh = blockIdx.x & 7;   // XCD-local
  const int cb = blockIdx.x >> 3;
  const int b = bh >> 2, h = bh & 3;
  const int col = cb * 4 + wave;

  // rolling pointers (float4 units); kp biased +128 so kA=-128, kB=+128 (±2048B offsets)
  const float4* kp = kb + ((size_t)(b * 1024) * 4 + h) * 64 + lane + 128;
  const float4* qp = qb + ((size_t)(b * 512) * 4 + h) * 64 + lane;
  const float4* vp = vb + ((size_t)(b * 512) * 4 + h) * 256 + col;
  const float4* rp = rb + ((size_t)(b * 512) * 4 + h) * 6;
  float* op = o + (size_t)(b * 1024) * NTOT + h * 256 + col;

  float sx = 0.f, sy = 0.f;

  float4 AkA, AkB, Aqv, Avv, AR0, AR1, AR2, AR3, AR4, AR5;
  float4 BkA, BkB, Bqv, Bvv, BR0, BR1, BR2, BR3, BR4, BR5;

#define LOADQ(P) { \
    P##kA = kp[-128]; \
    P##kB = kp[128]; \
    P##qv = qp[0]; \
    P##vv = vp[0]; \
    P##R0 = rp[0]; \
    P##R1 = rp[1]; \
    P##R2 = rp[2]; \
    P##R3 = rp[3]; \
    P##R4 = rp[4]; \
    P##R5 = rp[5]; \
    kp += 512; qp += 256; vp += 1024; rp += 24; }

#define STEPQ(P) { \
    float r[6]; \
    r[0] = P##kA.x * sx + P##kA.y * sy; \
    r[1] = P##kA.z * sx + P##kA.w * sy; \
    r[2] = P##kB.x * sx + P##kB.y * sy; \
    r[3] = P##kB.z * sx + P##kB.w * sy; \
    r[4] = P##qv.x * sx + P##qv.y * sy; \
    r[5] = P##qv.z * sx + P##qv.w * sy; \
    dpp_reduce(r); \
    float c0 = fmaf(-P##R0.x, r[0], P##R3.w * P##vv.x); \
    float c1 = fmaf(-P##R0.z, c0, fmaf(-P##R0.y, r[1], P##R5.x * P##vv.y)); \
    float c2 = fmaf(-P##R1.z, c1, fmaf(-P##R1.y, c0, fmaf(-P##R1.x, r[2], P##R5.y * P##vv.z))); \
    float c3 = fmaf(-P##R2.w, c2, fmaf(-P##R2.z, c1, fmaf(-P##R2.y, c0, \
               fmaf(-P##R2.x, r[3], P##R5.z * P##vv.w)))); \
    float ot = fmaf(P##R3.y, c1, fmaf(P##R3.x, c0, P##R0.w * r[4])); \
    float ot1 = fmaf(P##R4.w, c3, fmaf(P##R4.z, c2, fmaf(P##R4.y, c1, \
                fmaf(P##R4.x, c0, P##R3.z * r[5])))); \
    float g0 = P##R1.w * c0, g1 = P##R1.w * c1; \
    sx = fmaf(c3, P##kB.z, fmaf(c2, P##kB.x, fmaf(g1, P##kA.z, fmaf(g0, P##kA.x, P##R3.z * sx)))); \
    sy = fmaf(c3, P##kB.w, fmaf(c2, P##kB.y, fmaf(g1, P##kA.w, fmaf(g0, P##kA.y, P##R3.z * sy)))); \
    if (lane == 0) { op[0] = ot; op[NTOT] = ot1; } \
    op += 2 * NTOT; }

  LOADQ(A)
  LOADQ(B)
  for (int it = 0; it < 255; ++it) {
    STEPQ(A) LOADQ(A)
    STEPQ(B) LOADQ(B)
  }
  STEPQ(A)
  STEPQ(B)
#undef LOADQ
#undef STEPQ
}

// ---------------- RMSNorm(o) * w * SiLU(gate); writes dense bf16 [M][1024]
__global__ __launch_bounds__(256) void post_norm_gate(const float* __restrict__ o,
                                                      const float* __restrict__ gate,
                                                      const float* __restrict__ w,
                                                      ushort* __restrict__ obf) {
  int rb = blockIdx.x;
  int bt = rb >> 2, h = rb & 3;
  int tid = threadIdx.x;
  size_t ob = (size_t)bt * NTOT + h * 256 + tid;
  float ov = o[ob];
  float ss = wave_sum(ov * ov);
  __shared__ float sred[4];
  if ((tid & 63) == 0) sred[tid >> 6] = ss;
  __syncthreads();
  float tot = sred[0] + sred[1] + sred[2] + sred[3];
  float rms = rsqrtf(tot * (1.f / 256.f) + 1e-5f);
  float gt = gate[(size_t)bt * NTOT + h * 256 + tid];
  float val = ov * rms * w[tid] * (gt / (1.f + expf(-gt)));
  obf[(size_t)bt * HID + h * 256 + tid] = f2bf(val);
}

extern "C" void kernel_launch(void* const* d_in, const int* in_sizes, int n_in,
                              void* d_out, int out_size, void* d_ws, size_t ws_size,
                              hipStream_t stream) {
  const float* hs      = (const float*)d_in[0];
  const float* Wq      = (const float*)d_in[1];
  const float* Wk      = (const float*)d_in[2];
  const float* Wv      = (const float*)d_in[3];
  const float* Wb      = (const float*)d_in[4];
  const float* Wa      = (const float*)d_in[5];
  const float* Wg      = (const float*)d_in[6];
  const float* Wo      = (const float*)d_in[7];
  const float* A_log   = (const float*)d_in[8];
  const float* dt_bias = (const float*)d_in[9];
  const float* wq_conv = (const float*)d_in[10];
  const float* wk_conv = (const float*)d_in[11];
  const float* wv_conv = (const float*)d_in[12];
  const float* o_w     = (const float*)d_in[13];
  float* out = (float*)d_out;

  const int B = 2, T = 1024, M = B * T;

  float* ws    = (float*)d_ws;
  float* qkvg  = ws;                          // M*4608 fp32; cols 0..1023 get o; 3584+ gate
  float* kbuf  = qkvg + (size_t)M * NTOT;     // M*1024 (k interleaved)
  float* vbuf  = kbuf + (size_t)M * 1024;     // M*2048 (v pair-major)
  float* betab = vbuf + (size_t)M * 2048;     // M*8
  float* gb    = betab + (size_t)M * 8;       // M*4 (gamma)
  float* recb  = gb + (size_t)M * 4;          // 4096*24 floats
  float* qbuf  = out;                         // M*512 scratch (q pair-interleaved)

  // time-disjoint bf16 aliases in kbuf/vbuf regions:
  ushort* bqkvgT = (ushort*)kbuf;
  ushort* hsb    = (ushort*)(vbuf + (size_t)524288);  // vbuf + 2MB
  ushort* woT = (ushort*)kbuf;
  ushort* obf = (ushort*)vbuf;

  // casts + projections
  cast_hs<<<(M * HID / 4) / 256, 256, 0, stream>>>(hs, hsb);
  tr_pack<<<dim3(NTOT / 32, HID / 32), 256, 0, stream>>>(Wq, Wk, Wv, Wg, bqkvgT);
  gemm_bf16<<<dim3(NTOT / 128, M / 128), 256, 0, stream>>>(hsb, bqkvgT, qkvg, HID, NTOT);
  proj_bg<<<M, 256, 0, stream>>>(hs, Wb, Wa, A_log, dt_bias, betab, gb);
  // conv + SiLU (+ l2norm q,k) into scan-friendly layouts
  conv_q<<<M * 4, 128, 0, stream>>>(qkvg + 0, NTOT, wq_conv, qbuf, T);
  conv_k<<<M * 8, 128, 0, stream>>>(qkvg + 512, NTOT, wk_conv, kbuf, T);
  conv_v<<<M * 8, 256, 0, stream>>>(qkvg + 1536, NTOT, wv_conv, vbuf, T);
  // 2-step coefficient records
  cross_dots2<<<M * H / 8, 256, 0, stream>>>(kbuf, qbuf, betab, gb, recb);
  // batched scan -> o into qkvg cols 0..1023
  scan2<<<512, 256, 0, stream>>>((const float4*)kbuf, (const float4*)qbuf,
                                 (const float4*)vbuf, (const float4*)recb, qkvg);
  // epilogue + output projection
  post_norm_gate<<<M * H, 256, 0, stream>>>(qkvg, qkvg + 3584, o_w, obf);
  tr_one<<<dim3(HID / 32, HID / 32), 256, 0, stream>>>(Wo, woT, HID);
  gemm_bf16<<<dim3(HID / 128, M / 128), 256, 0, stream>>>(obf, woT, out, HID, HID);
}

// Round 18
// 424.492 us; speedup vs baseline: 1.2462x; 1.0083x over previous
//
#include <hip/hip_runtime.h>
#include <cstdint>
#include <cstddef>

#define H 4
#define DK 128
#define DV 256
#define NH 2
#define HID 1024
#define KSZ 4
#define NTOT 4608  // packed projection width: 512 q | 1024 k | 2048 v | 1024 g

typedef __bf16 bfx8 __attribute__((ext_vector_type(8)));
typedef float f32x4 __attribute__((ext_vector_type(4)));

__device__ __forceinline__ float wave_sum(float x) {
#pragma unroll
  for (int off = 1; off < 64; off <<= 1) x += __shfl_xor(x, off, 64);
  return x;
}

__device__ __forceinline__ ushort f2bf(float x) {
  uint u = __float_as_uint(x);
  return (ushort)((u + 0x7fffu + ((u >> 16) & 1u)) >> 16);
}

#define DPP_ADD(x, ctrl) \
  x += __int_as_float(__builtin_amdgcn_update_dpp(0, __float_as_int(x), ctrl, 0xf, 0xf, true))

// N independent full-wave64 sums (6-stage); results uniform via readlane(63)
template <int N>
__device__ __forceinline__ void dpp_reduce(float (&d)[N]) {
#pragma unroll
  for (int i = 0; i < N; i++) DPP_ADD(d[i], 0x111);
#pragma unroll
  for (int i = 0; i < N; i++) DPP_ADD(d[i], 0x112);
#pragma unroll
  for (int i = 0; i < N; i++) DPP_ADD(d[i], 0x114);
#pragma unroll
  for (int i = 0; i < N; i++) DPP_ADD(d[i], 0x118);
#pragma unroll
  for (int i = 0; i < N; i++) DPP_ADD(d[i], 0x142);
#pragma unroll
  for (int i = 0; i < N; i++) DPP_ADD(d[i], 0x143);
#pragma unroll
  for (int i = 0; i < N; i++)
    d[i] = __int_as_float(__builtin_amdgcn_readlane(__float_as_int(d[i]), 63));
}

// ---------------- fp32 -> bf16 cast
__global__ __launch_bounds__(256) void cast_hs(const float* __restrict__ src,
                                               ushort* __restrict__ dst) {
  int i = blockIdx.x * 256 + threadIdx.x;
  float4 v = ((const float4*)src)[i];
  ushort4 o = {f2bf(v.x), f2bf(v.y), f2bf(v.z), f2bf(v.w)};
  ((ushort4*)dst)[i] = o;
}

// ---------------- transpose+cast packed weights
__global__ __launch_bounds__(256) void tr_pack(const float* __restrict__ Wq,
                                               const float* __restrict__ Wk,
                                               const float* __restrict__ Wv,
                                               const float* __restrict__ Wg,
                                               ushort* __restrict__ Bt) {
  __shared__ float tile[32][33];
  int n0 = blockIdx.x * 32, k0 = blockIdx.y * 32;
  const float* src;
  int ld, nb;
  if (n0 < 512)       { src = Wq; ld = 512;  nb = n0; }
  else if (n0 < 1536) { src = Wk; ld = 1024; nb = n0 - 512; }
  else if (n0 < 3584) { src = Wv; ld = 2048; nb = n0 - 1536; }
  else                { src = Wg; ld = 1024; nb = n0 - 3584; }
  int tx = threadIdx.x & 31, ty = threadIdx.x >> 5;
#pragma unroll
  for (int i = 0; i < 4; i++)
    tile[ty + i * 8][tx] = src[(size_t)(k0 + ty + i * 8) * ld + nb + tx];
  __syncthreads();
#pragma unroll
  for (int i = 0; i < 4; i++)
    Bt[(size_t)(n0 + ty + i * 8) * 1024 + k0 + tx] = f2bf(tile[tx][ty + i * 8]);
}

__global__ __launch_bounds__(256) void tr_one(const float* __restrict__ W,
                                              ushort* __restrict__ Bt, int N) {
  __shared__ float tile[32][33];
  int n0 = blockIdx.x * 32, k0 = blockIdx.y * 32;
  int tx = threadIdx.x & 31, ty = threadIdx.x >> 5;
#pragma unroll
  for (int i = 0; i < 4; i++)
    tile[ty + i * 8][tx] = W[(size_t)(k0 + ty + i * 8) * N + n0 + tx];
  __syncthreads();
#pragma unroll
  for (int i = 0; i < 4; i++)
    Bt[(size_t)(n0 + ty + i * 8) * 1024 + k0 + tx] = f2bf(tile[tx][ty + i * 8]);
}

// ---------------- bf16 MFMA GEMM
#define LDP 40
__global__ __launch_bounds__(256) void gemm_bf16(const ushort* __restrict__ A,
                                                 const ushort* __restrict__ Bt,
                                                 float* __restrict__ C,
                                                 int K, int ldc) {
  __shared__ __align__(16) ushort As[128][LDP];
  __shared__ __align__(16) ushort Bs[128][LDP];
  const int tid = threadIdx.x;
  const int lane = tid & 63, wave = tid >> 6;
  const int wr = wave >> 1, wc = wave & 1;
  const int row0 = blockIdx.y * 128, col0 = blockIdx.x * 128;
  const int r = tid >> 1, hf = tid & 1;

  f32x4 acc[4][4];
#pragma unroll
  for (int i = 0; i < 4; i++)
#pragma unroll
    for (int j = 0; j < 4; j++) acc[i][j] = {0.f, 0.f, 0.f, 0.f};

  const int lrow = lane & 15, lk = (lane >> 4) * 8;

  for (int k0 = 0; k0 < K; k0 += 32) {
    const float4* pa = (const float4*)(A + (size_t)(row0 + r) * K + k0 + hf * 16);
    const float4* pb = (const float4*)(Bt + (size_t)(col0 + r) * K + k0 + hf * 16);
    float4 a0 = pa[0], a1 = pa[1];
    float4 b0 = pb[0], b1 = pb[1];
    __syncthreads();
    *(float4*)&As[r][hf * 16] = a0;
    *(float4*)&As[r][hf * 16 + 8] = a1;
    *(float4*)&Bs[r][hf * 16] = b0;
    *(float4*)&Bs[r][hf * 16 + 8] = b1;
    __syncthreads();
    bfx8 af[4], bf[4];
#pragma unroll
    for (int mf = 0; mf < 4; mf++)
      af[mf] = *(const bfx8*)&As[wr * 64 + mf * 16 + lrow][lk];
#pragma unroll
    for (int nf = 0; nf < 4; nf++)
      bf[nf] = *(const bfx8*)&Bs[wc * 64 + nf * 16 + lrow][lk];
#pragma unroll
    for (int mf = 0; mf < 4; mf++)
#pragma unroll
      for (int nf = 0; nf < 4; nf++)
        acc[mf][nf] = __builtin_amdgcn_mfma_f32_16x16x32_bf16(af[mf], bf[nf], acc[mf][nf], 0, 0, 0);
  }
  const int crow = (lane >> 4) * 4, ccol = lane & 15;
#pragma unroll
  for (int mf = 0; mf < 4; mf++)
#pragma unroll
    for (int nf = 0; nf < 4; nf++)
#pragma unroll
      for (int rr = 0; rr < 4; rr++)
        C[(size_t)(row0 + wr * 64 + mf * 16 + crow + rr) * ldc + col0 + wc * 64 + nf * 16 + ccol] =
            acc[mf][nf][rr];
}

// ---------------- beta / gamma tiny projections (gamma = exp(g))
__global__ __launch_bounds__(256) void proj_bg(const float* __restrict__ hs,
                                               const float* __restrict__ Wb,
                                               const float* __restrict__ Wa,
                                               const float* __restrict__ A_log,
                                               const float* __restrict__ dt_bias,
                                               float* __restrict__ beta,
                                               float* __restrict__ g) {
  int row = blockIdx.x;
  int lane = threadIdx.x & 63;
  int wave = threadIdx.x >> 6;
  const float* x = hs + (size_t)row * HID;
  for (int out = wave; out < 12; out += 4) {
    float sum = 0.f;
    if (out < 8) {
      for (int k = lane; k < HID; k += 64) sum = fmaf(x[k], Wb[(size_t)k * 8 + out], sum);
    } else {
      int c = out - 8;
      for (int k = lane; k < HID; k += 64) sum = fmaf(x[k], Wa[(size_t)k * 4 + c], sum);
    }
    sum = wave_sum(sum);
    if (lane == 0) {
      if (out < 8) {
        beta[(size_t)row * 8 + out] = 2.f / (1.f + expf(-sum));
      } else {
        int h = out - 8;
        float xx = sum + dt_bias[h];
        float sp = (xx > 20.f) ? xx : log1pf(expf(xx));
        g[(size_t)row * 4 + h] = expf(-expf(A_log[h]) * sp);  // gamma
      }
    }
  }
}

// ---------------- conv+SiLU+l2norm for q -> pair-interleaved layout
__global__ __launch_bounds__(128) void conv_q(const float* __restrict__ x, int ldx,
                                              const float* __restrict__ w,
                                              float* __restrict__ y, int T) {
  int rb = blockIdx.x;
  int h = rb % 4;
  int bt = rb / 4;
  int t = bt % T;
  int b = bt / T;
  int d = threadIdx.x;
  int c = h * 128 + d;
  const float* wc = w + (size_t)c * KSZ;
  float acc = 0.f;
#pragma unroll
  for (int i = 0; i < KSZ; i++) {
    int tt = t - (KSZ - 1) + i;
    if (tt >= 0) acc = fmaf(x[(size_t)(b * T + tt) * ldx + c], wc[i], acc);
  }
  float val = acc / (1.f + expf(-acc));
  float ss = wave_sum(val * val);
  __shared__ float sred[2];
  if ((threadIdx.x & 63) == 0) sred[threadIdx.x >> 6] = ss;
  __syncthreads();
  val *= rsqrtf(sred[0] + sred[1] + 1e-6f);
  y[((size_t)(b * 512 + (t >> 1)) * 4 + h) * 256 + (d >> 1) * 4 + (d & 1) + (t & 1) * 2] = val;
}

// ---------------- conv+SiLU+l2norm for k -> copy-interleaved layout
__global__ __launch_bounds__(128) void conv_k(const float* __restrict__ x, int ldx,
                                              const float* __restrict__ w,
                                              float* __restrict__ y, int T) {
  int rb = blockIdx.x;
  int gi = rb % 8;  // i*4 + h
  int bt = rb / 8;
  int t = bt % T;
  int b = bt / T;
  int i = gi >> 2, h = gi & 3;
  int d = threadIdx.x;
  int c = i * 512 + h * 128 + d;
  const float* wc = w + (size_t)c * KSZ;
  float acc = 0.f;
#pragma unroll
  for (int kk = 0; kk < KSZ; kk++) {
    int tt = t - (KSZ - 1) + kk;
    if (tt >= 0) acc = fmaf(x[(size_t)(b * T + tt) * ldx + c], wc[kk], acc);
  }
  float val = acc / (1.f + expf(-acc));
  float ss = wave_sum(val * val);
  __shared__ float sred[2];
  if ((threadIdx.x & 63) == 0) sred[threadIdx.x >> 6] = ss;
  __syncthreads();
  val *= rsqrtf(sred[0] + sred[1] + 1e-6f);
  y[((size_t)(b * T + t) * 4 + h) * 256 + (d >> 1) * 4 + (d & 1) + i * 2] = val;
}

// ---------------- conv+SiLU for v -> pair-major layout
__global__ __launch_bounds__(256) void conv_v(const float* __restrict__ x, int ldx,
                                              const float* __restrict__ w,
                                              float* __restrict__ y, int T) {
  int rb = blockIdx.x;
  int gi = rb % 8;  // i*4 + h
  int bt = rb / 8;
  int t = bt % T;
  int b = bt / T;
  int i = gi >> 2, h = gi & 3;
  int d = threadIdx.x;
  int c = i * 1024 + h * 256 + d;
  const float* wc = w + (size_t)c * KSZ;
  float acc = 0.f;
#pragma unroll
  for (int kk = 0; kk < KSZ; kk++) {
    int tt = t - (KSZ - 1) + kk;
    if (tt >= 0) acc = fmaf(x[(size_t)(b * T + tt) * ldx + c], wc[kk], acc);
  }
  float val = acc / (1.f + expf(-acc));
  y[((size_t)(b * 512 + (t >> 1)) * 4 + h) * 1024 + d * 4 + (t & 1) * 2 + i] = val;
}

// ---------------- 2-step coefficient records (24 floats per (b,tp,h))
__global__ __launch_bounds__(256) void cross_dots2(const float* __restrict__ kbuf2,
                                                   const float* __restrict__ qbuf2,
                                                   const float* __restrict__ beta,
                                                   const float* __restrict__ gam,
                                                   float* __restrict__ rec) {
  int idx = blockIdx.x * 4 + (threadIdx.x >> 6);  // (b*512+tp)*4 + h
  int lane = threadIdx.x & 63;
  int h = idx & 3, tp = (idx >> 2) & 511, b = idx >> 11;
  int t = 2 * tp;
  const float4 kA = *(const float4*)&kbuf2[((size_t)(b * 1024 + t) * 4 + h) * 256 + lane * 4];
  const float4 kB = *(const float4*)&kbuf2[((size_t)(b * 1024 + t + 1) * 4 + h) * 256 + lane * 4];
  const float4 qv = *(const float4*)&qbuf2[(size_t)idx * 256 + lane * 4];
  float d[12];
  d[0] = kA.z * kA.x + kA.w * kA.y;   // d10
  d[1] = kB.x * kA.x + kB.y * kA.y;   // d20
  d[2] = kB.x * kA.z + kB.y * kA.w;   // d21
  d[3] = kB.z * kA.x + kB.w * kA.y;   // d30
  d[4] = kB.z * kA.z + kB.w * kA.w;   // d31
  d[5] = kB.z * kB.x + kB.w * kB.y;   // d32
  d[6] = qv.x * kA.x + qv.y * kA.y;   // e00
  d[7] = qv.x * kA.z + qv.y * kA.w;   // e01
  d[8] = qv.z * kA.x + qv.w * kA.y;   // e10
  d[9] = qv.z * kA.z + qv.w * kA.w;   // e11
  d[10] = qv.z * kB.x + qv.w * kB.y;  // e12
  d[11] = qv.z * kB.z + qv.w * kB.w;  // e13
  dpp_reduce(d);
  int bt = b * 1024 + t;
  float b0 = beta[(size_t)(bt * 2 + 0) * 4 + h];
  float b1 = beta[(size_t)(bt * 2 + 1) * 4 + h];
  float b2 = beta[(size_t)(bt * 2 + 2) * 4 + h];
  float b3 = beta[(size_t)(bt * 2 + 3) * 4 + h];
  float gt = gam[(size_t)bt * 4 + h];
  float gt1 = gam[(size_t)(bt + 1) * 4 + h];
  if (lane == 0) {
    float G2 = gt * gt1;
    float4* rp = (float4*)&rec[(size_t)idx * 24];
    rp[0] = {b0 * gt, b1 * gt, b1 * d[0], gt};
    rp[1] = {b2 * G2, b2 * gt1 * d[1], b2 * gt1 * d[2], gt1};
    rp[2] = {b3 * G2, b3 * gt1 * d[3], b3 * gt1 * d[4], b3 * d[5]};
    rp[3] = {d[6], d[7], G2, b0};
    rp[4] = {gt1 * d[8], gt1 * d[9], d[10], d[11]};
    rp[5] = {b1, b2, b3, 0.f};
  }
}

// ---------------- 2-step batched gated-delta scan, one wave per (b,h,dv-column)
// R14 config + sched_barrier(0) after each LOADQ: forbids the scheduler from
// sinking the prefetch loads into the consuming STEPQs (VGPR=56 proved the
// depth-2 FIFO was NOT register-resident; sinking re-exposes L2 latency and
// re-materializes addressing). Loads stay plain C++ -> compiler owns all
// s_waitcnt insertion; zero correctness risk (unlike the R11/R12 asm route).
__global__ __launch_bounds__(256, 2) void scan2(const float4* __restrict__ kb,
                                                const float4* __restrict__ qb,
                                                const float4* __restrict__ vb,
                                                const float4* __restrict__ rb,
                                                float* __restrict__ o) {
  const int lane = threadIdx.x & 63;
  const int wave = __builtin_amdgcn_readfirstlane(threadIdx.x >> 6);
  const int bh = blockIdx.x & 7;   // XCD-local
  const int cb = blockIdx.x >> 3;
  const int b = bh >> 2, h = bh & 3;
  const int col = cb * 4 + wave;

  // rolling pointers (float4 units); kp biased +128 so kA=-128, kB=+128 (±2048B offsets)
  const float4* kp = kb + ((size_t)(b * 1024) * 4 + h) * 64 + lane + 128;
  const float4* qp = qb + ((size_t)(b * 512) * 4 + h) * 64 + lane;
  const float4* vp = vb + ((size_t)(b * 512) * 4 + h) * 256 + col;
  const float4* rp = rb + ((size_t)(b * 512) * 4 + h) * 6;
  float* op = o + (size_t)(b * 1024) * NTOT + h * 256 + col;

  float sx = 0.f, sy = 0.f;

  float4 AkA, AkB, Aqv, Avv, AR0, AR1, AR2, AR3, AR4, AR5;
  float4 BkA, BkB, Bqv, Bvv, BR0, BR1, BR2, BR3, BR4, BR5;

#define LOADQ(P) { \
    P##kA = kp[-128]; \
    P##kB = kp[128]; \
    P##qv = qp[0]; \
    P##vv = vp[0]; \
    P##R0 = rp[0]; \
    P##R1 = rp[1]; \
    P##R2 = rp[2]; \
    P##R3 = rp[3]; \
    P##R4 = rp[4]; \
    P##R5 = rp[5]; \
    kp += 512; qp += 256; vp += 1024; rp += 24; \
    __builtin_amdgcn_sched_barrier(0); }

#define STEPQ(P) { \
    float r[6]; \
    r[0] = P##kA.x * sx + P##kA.y * sy; \
    r[1] = P##kA.z * sx + P##kA.w * sy; \
    r[2] = P##kB.x * sx + P##kB.y * sy; \
    r[3] = P##kB.z * sx + P##kB.w * sy; \
    r[4] = P##qv.x * sx + P##qv.y * sy; \
    r[5] = P##qv.z * sx + P##qv.w * sy; \
    dpp_reduce(r); \
    float c0 = fmaf(-P##R0.x, r[0], P##R3.w * P##vv.x); \
    float c1 = fmaf(-P##R0.z, c0, fmaf(-P##R0.y, r[1], P##R5.x * P##vv.y)); \
    float c2 = fmaf(-P##R1.z, c1, fmaf(-P##R1.y, c0, fmaf(-P##R1.x, r[2], P##R5.y * P##vv.z))); \
    float c3 = fmaf(-P##R2.w, c2, fmaf(-P##R2.z, c1, fmaf(-P##R2.y, c0, \
               fmaf(-P##R2.x, r[3], P##R5.z * P##vv.w)))); \
    float ot = fmaf(P##R3.y, c1, fmaf(P##R3.x, c0, P##R0.w * r[4])); \
    float ot1 = fmaf(P##R4.w, c3, fmaf(P##R4.z, c2, fmaf(P##R4.y, c1, \
                fmaf(P##R4.x, c0, P##R3.z * r[5])))); \
    float g0 = P##R1.w * c0, g1 = P##R1.w * c1; \
    sx = fmaf(c3, P##kB.z, fmaf(c2, P##kB.x, fmaf(g1, P##kA.z, fmaf(g0, P##kA.x, P##R3.z * sx)))); \
    sy = fmaf(c3, P##kB.w, fmaf(c2, P##kB.y, fmaf(g1, P##kA.w, fmaf(g0, P##kA.y, P##R3.z * sy)))); \
    if (lane == 0) { op[0] = ot; op[NTOT] = ot1; } \
    op += 2 * NTOT; }

  LOADQ(A)
  LOADQ(B)
  for (int it = 0; it < 255; ++it) {
    STEPQ(A) LOADQ(A)
    STEPQ(B) LOADQ(B)
  }
  STEPQ(A)
  STEPQ(B)
#undef LOADQ
#undef STEPQ
}

// ---------------- RMSNorm(o) * w * SiLU(gate); writes dense bf16 [M][1024]
__global__ __launch_bounds__(256) void post_norm_gate(const float* __restrict__ o,
                                                      const float* __restrict__ gate,
                                                      const float* __restrict__ w,
                                                      ushort* __restrict__ obf) {
  int rb = blockIdx.x;
  int bt = rb >> 2, h = rb & 3;
  int tid = threadIdx.x;
  size_t ob = (size_t)bt * NTOT + h * 256 + tid;
  float ov = o[ob];
  float ss = wave_sum(ov * ov);
  __shared__ float sred[4];
  if ((tid & 63) == 0) sred[tid >> 6] = ss;
  __syncthreads();
  float tot = sred[0] + sred[1] + sred[2] + sred[3];
  float rms = rsqrtf(tot * (1.f / 256.f) + 1e-5f);
  float gt = gate[(size_t)bt * NTOT + h * 256 + tid];
  float val = ov * rms * w[tid] * (gt / (1.f + expf(-gt)));
  obf[(size_t)bt * HID + h * 256 + tid] = f2bf(val);
}

extern "C" void kernel_launch(void* const* d_in, const int* in_sizes, int n_in,
                              void* d_out, int out_size, void* d_ws, size_t ws_size,
                              hipStream_t stream) {
  const float* hs      = (const float*)d_in[0];
  const float* Wq      = (const float*)d_in[1];
  const float* Wk      = (const float*)d_in[2];
  const float* Wv      = (const float*)d_in[3];
  const float* Wb      = (const float*)d_in[4];
  const float* Wa      = (const float*)d_in[5];
  const float* Wg      = (const float*)d_in[6];
  const float* Wo      = (const float*)d_in[7];
  const float* A_log   = (const float*)d_in[8];
  const float* dt_bias = (const float*)d_in[9];
  const float* wq_conv = (const float*)d_in[10];
  const float* wk_conv = (const float*)d_in[11];
  const float* wv_conv = (const float*)d_in[12];
  const float* o_w     = (const float*)d_in[13];
  float* out = (float*)d_out;

  const int B = 2, T = 1024, M = B * T;

  float* ws    = (float*)d_ws;
  float* qkvg  = ws;                          // M*4608 fp32; cols 0..1023 get o; 3584+ gate
  float* kbuf  = qkvg + (size_t)M * NTOT;     // M*1024 (k interleaved)
  float* vbuf  = kbuf + (size_t)M * 1024;     // M*2048 (v pair-major)
  float* betab = vbuf + (size_t)M * 2048;     // M*8
  float* gb    = betab + (size_t)M * 8;       // M*4 (gamma)
  float* recb  = gb + (size_t)M * 4;          // 4096*24 floats
  float* qbuf  = out;                         // M*512 scratch (q pair-interleaved)

  // time-disjoint bf16 aliases in kbuf/vbuf regions:
  ushort* bqkvgT = (ushort*)kbuf;
  ushort* hsb    = (ushort*)(vbuf + (size_t)524288);  // vbuf + 2MB
  ushort* woT = (ushort*)kbuf;
  ushort* obf = (ushort*)vbuf;

  // casts + projections
  cast_hs<<<(M * HID / 4) / 256, 256, 0, stream>>>(hs, hsb);
  tr_pack<<<dim3(NTOT / 32, HID / 32), 256, 0, stream>>>(Wq, Wk, Wv, Wg, bqkvgT);
  gemm_bf16<<<dim3(NTOT / 128, M / 128), 256, 0, stream>>>(hsb, bqkvgT, qkvg, HID, NTOT);
  proj_bg<<<M, 256, 0, stream>>>(hs, Wb, Wa, A_log, dt_bias, betab, gb);
  // conv + SiLU (+ l2norm q,k) into scan-friendly layouts
  conv_q<<<M * 4, 128, 0, stream>>>(qkvg + 0, NTOT, wq_conv, qbuf, T);
  conv_k<<<M * 8, 128, 0, stream>>>(qkvg + 512, NTOT, wk_conv, kbuf, T);
  conv_v<<<M * 8, 256, 0, stream>>>(qkvg + 1536, NTOT, wv_conv, vbuf, T);
  // 2-step coefficient records
  cross_dots2<<<M * H / 8, 256, 0, stream>>>(kbuf, qbuf, betab, gb, recb);
  // batched scan -> o into qkvg cols 0..1023
  scan2<<<512, 256, 0, stream>>>((const float4*)kbuf, (const float4*)qbuf,
                                 (const float4*)vbuf, (const float4*)recb, qkvg);
  // epilogue + output projection
  post_norm_gate<<<M * H, 256, 0, stream>>>(qkvg, qkvg + 3584, o_w, obf);
  tr_one<<<dim3(HID / 32, HID / 32), 256, 0, stream>>>(Wo, woT, HID);
  gemm_bf16<<<dim3(HID / 128, M / 128), 256, 0, stream>>>(obf, woT, out, HID, HID);
}

// Round 19
// 419.579 us; speedup vs baseline: 1.2607x; 1.0117x over previous
//
#include <hip/hip_runtime.h>
#include <cstdint>
#include <cstddef>

#define H 4
#define DK 128
#define DV 256
#define NH 2
#define HID 1024
#define KSZ 4
#define NTOT 4608  // packed projection width: 512 q | 1024 k | 2048 v | 1024 g

typedef __bf16 bfx8 __attribute__((ext_vector_type(8)));
typedef float f32x4 __attribute__((ext_vector_type(4)));

typedef __attribute__((address_space(1))) const void GVOID;
typedef __attribute__((address_space(3))) void LVOID;
#define GLL(g, l) __builtin_amdgcn_global_load_lds((GVOID*)(g), (LVOID*)(l), 16, 0, 0)

__device__ __forceinline__ float wave_sum(float x) {
#pragma unroll
  for (int off = 1; off < 64; off <<= 1) x += __shfl_xor(x, off, 64);
  return x;
}

__device__ __forceinline__ ushort f2bf(float x) {
  uint u = __float_as_uint(x);
  return (ushort)((u + 0x7fffu + ((u >> 16) & 1u)) >> 16);
}

#define DPP_ADD(x, ctrl) \
  x += __int_as_float(__builtin_amdgcn_update_dpp(0, __float_as_int(x), ctrl, 0xf, 0xf, true))

// N independent full-wave64 sums (6-stage); results uniform via readlane(63)
template <int N>
__device__ __forceinline__ void dpp_reduce(float (&d)[N]) {
#pragma unroll
  for (int i = 0; i < N; i++) DPP_ADD(d[i], 0x111);
#pragma unroll
  for (int i = 0; i < N; i++) DPP_ADD(d[i], 0x112);
#pragma unroll
  for (int i = 0; i < N; i++) DPP_ADD(d[i], 0x114);
#pragma unroll
  for (int i = 0; i < N; i++) DPP_ADD(d[i], 0x118);
#pragma unroll
  for (int i = 0; i < N; i++) DPP_ADD(d[i], 0x142);
#pragma unroll
  for (int i = 0; i < N; i++) DPP_ADD(d[i], 0x143);
#pragma unroll
  for (int i = 0; i < N; i++)
    d[i] = __int_as_float(__builtin_amdgcn_readlane(__float_as_int(d[i]), 63));
}

// ---------------- fp32 -> bf16 cast
__global__ __launch_bounds__(256) void cast_hs(const float* __restrict__ src,
                                               ushort* __restrict__ dst) {
  int i = blockIdx.x * 256 + threadIdx.x;
  float4 v = ((const float4*)src)[i];
  ushort4 o = {f2bf(v.x), f2bf(v.y), f2bf(v.z), f2bf(v.w)};
  ((ushort4*)dst)[i] = o;
}

// ---------------- transpose+cast packed weights
__global__ __launch_bounds__(256) void tr_pack(const float* __restrict__ Wq,
                                               const float* __restrict__ Wk,
                                               const float* __restrict__ Wv,
                                               const float* __restrict__ Wg,
                                               ushort* __restrict__ Bt) {
  __shared__ float tile[32][33];
  int n0 = blockIdx.x * 32, k0 = blockIdx.y * 32;
  const float* src;
  int ld, nb;
  if (n0 < 512)       { src = Wq; ld = 512;  nb = n0; }
  else if (n0 < 1536) { src = Wk; ld = 1024; nb = n0 - 512; }
  else if (n0 < 3584) { src = Wv; ld = 2048; nb = n0 - 1536; }
  else                { src = Wg; ld = 1024; nb = n0 - 3584; }
  int tx = threadIdx.x & 31, ty = threadIdx.x >> 5;
#pragma unroll
  for (int i = 0; i < 4; i++)
    tile[ty + i * 8][tx] = src[(size_t)(k0 + ty + i * 8) * ld + nb + tx];
  __syncthreads();
#pragma unroll
  for (int i = 0; i < 4; i++)
    Bt[(size_t)(n0 + ty + i * 8) * 1024 + k0 + tx] = f2bf(tile[tx][ty + i * 8]);
}

__global__ __launch_bounds__(256) void tr_one(const float* __restrict__ W,
                                              ushort* __restrict__ Bt, int N) {
  __shared__ float tile[32][33];
  int n0 = blockIdx.x * 32, k0 = blockIdx.y * 32;
  int tx = threadIdx.x & 31, ty = threadIdx.x >> 5;
#pragma unroll
  for (int i = 0; i < 4; i++)
    tile[ty + i * 8][tx] = W[(size_t)(k0 + ty + i * 8) * N + n0 + tx];
  __syncthreads();
#pragma unroll
  for (int i = 0; i < 4; i++)
    Bt[(size_t)(n0 + ty + i * 8) * 1024 + k0 + tx] = f2bf(tile[tx][ty + i * 8]);
}

// ---------------- bf16 MFMA GEMM with global_load_lds staging (m97 recipe)
// A-tile/B-tile [128][32] ushort LINEAR (global_load_lds writes base+lane*16;
// per-lane src row=16c+(lane>>2), col=(lane&3)*8 makes that exactly row-major).
__global__ __launch_bounds__(256) void gemm_bf16(const ushort* __restrict__ A,
                                                 const ushort* __restrict__ Bt,
                                                 float* __restrict__ C,
                                                 int K, int ldc) {
  __shared__ __align__(16) ushort As[128][32];
  __shared__ __align__(16) ushort Bs[128][32];
  const int tid = threadIdx.x;
  const int lane = tid & 63, wave = tid >> 6;
  const int wr = wave >> 1, wc = wave & 1;
  const int row0 = blockIdx.y * 128, col0 = blockIdx.x * 128;

  // staging: 8 chunks of 16 rows per operand; wave w stages chunks 2w, 2w+1
  const int ra = wave * 32 + (lane >> 2);
  const int rb = ra + 16;
  const int kc = (lane & 3) * 8;
  const ushort* pa0 = A + (size_t)(row0 + ra) * K + kc;
  const ushort* pa1 = A + (size_t)(row0 + rb) * K + kc;
  const ushort* pb0 = Bt + (size_t)(col0 + ra) * K + kc;
  const ushort* pb1 = Bt + (size_t)(col0 + rb) * K + kc;
  ushort* lA0 = &As[wave * 32][0];
  ushort* lA1 = &As[wave * 32 + 16][0];
  ushort* lB0 = &Bs[wave * 32][0];
  ushort* lB1 = &Bs[wave * 32 + 16][0];

  f32x4 acc[4][4];
#pragma unroll
  for (int i = 0; i < 4; i++)
#pragma unroll
    for (int j = 0; j < 4; j++) acc[i][j] = {0.f, 0.f, 0.f, 0.f};

  const int lrow = lane & 15, lk = (lane >> 4) * 8;

  for (int k0 = 0; k0 < K; k0 += 32) {
    __syncthreads();  // previous compute done reading LDS
    GLL(pa0, lA0);
    GLL(pa1, lA1);
    GLL(pb0, lB0);
    GLL(pb1, lB1);
    pa0 += 32; pa1 += 32; pb0 += 32; pb1 += 32;
    __syncthreads();  // drains vmcnt -> tiles resident
    bfx8 af[4], bf[4];
#pragma unroll
    for (int mf = 0; mf < 4; mf++)
      af[mf] = *(const bfx8*)&As[wr * 64 + mf * 16 + lrow][lk];
#pragma unroll
    for (int nf = 0; nf < 4; nf++)
      bf[nf] = *(const bfx8*)&Bs[wc * 64 + nf * 16 + lrow][lk];
#pragma unroll
    for (int mf = 0; mf < 4; mf++)
#pragma unroll
      for (int nf = 0; nf < 4; nf++)
        acc[mf][nf] = __builtin_amdgcn_mfma_f32_16x16x32_bf16(af[mf], bf[nf], acc[mf][nf], 0, 0, 0);
  }
  // epilogue: C/D layout col=lane&15, row=(lane>>4)*4+reg
  const int crow = (lane >> 4) * 4, ccol = lane & 15;
#pragma unroll
  for (int mf = 0; mf < 4; mf++)
#pragma unroll
    for (int nf = 0; nf < 4; nf++)
#pragma unroll
      for (int rr = 0; rr < 4; rr++)
        C[(size_t)(row0 + wr * 64 + mf * 16 + crow + rr) * ldc + col0 + wc * 64 + nf * 16 + ccol] =
            acc[mf][nf][rr];
}

// ---------------- beta / gamma tiny projections (gamma = exp(g))
__global__ __launch_bounds__(256) void proj_bg(const float* __restrict__ hs,
                                               const float* __restrict__ Wb,
                                               const float* __restrict__ Wa,
                                               const float* __restrict__ A_log,
                                               const float* __restrict__ dt_bias,
                                               float* __restrict__ beta,
                                               float* __restrict__ g) {
  int row = blockIdx.x;
  int lane = threadIdx.x & 63;
  int wave = threadIdx.x >> 6;
  const float* x = hs + (size_t)row * HID;
  for (int out = wave; out < 12; out += 4) {
    float sum = 0.f;
    if (out < 8) {
      for (int k = lane; k < HID; k += 64) sum = fmaf(x[k], Wb[(size_t)k * 8 + out], sum);
    } else {
      int c = out - 8;
      for (int k = lane; k < HID; k += 64) sum = fmaf(x[k], Wa[(size_t)k * 4 + c], sum);
    }
    sum = wave_sum(sum);
    if (lane == 0) {
      if (out < 8) {
        beta[(size_t)row * 8 + out] = 2.f / (1.f + expf(-sum));
      } else {
        int h = out - 8;
        float xx = sum + dt_bias[h];
        float sp = (xx > 20.f) ? xx : log1pf(expf(xx));
        g[(size_t)row * 4 + h] = expf(-expf(A_log[h]) * sp);  // gamma
      }
    }
  }
}

// ---------------- conv+SiLU+l2norm for q -> pair-interleaved layout
__global__ __launch_bounds__(128) void conv_q(const float* __restrict__ x, int ldx,
                                              const float* __restrict__ w,
                                              float* __restrict__ y, int T) {
  int rb = blockIdx.x;
  int h = rb % 4;
  int bt = rb / 4;
  int t = bt % T;
  int b = bt / T;
  int d = threadIdx.x;
  int c = h * 128 + d;
  const float* wc = w + (size_t)c * KSZ;
  float acc = 0.f;
#pragma unroll
  for (int i = 0; i < KSZ; i++) {
    int tt = t - (KSZ - 1) + i;
    if (tt >= 0) acc = fmaf(x[(size_t)(b * T + tt) * ldx + c], wc[i], acc);
  }
  float val = acc / (1.f + expf(-acc));
  float ss = wave_sum(val * val);
  __shared__ float sred[2];
  if ((threadIdx.x & 63) == 0) sred[threadIdx.x >> 6] = ss;
  __syncthreads();
  val *= rsqrtf(sred[0] + sred[1] + 1e-6f);
  y[((size_t)(b * 512 + (t >> 1)) * 4 + h) * 256 + (d >> 1) * 4 + (d & 1) + (t & 1) * 2] = val;
}

// ---------------- conv+SiLU+l2norm for k -> copy-interleaved layout
__global__ __launch_bounds__(128) void conv_k(const float* __restrict__ x, int ldx,
                                              const float* __restrict__ w,
                                              float* __restrict__ y, int T) {
  int rb = blockIdx.x;
  int gi = rb % 8;  // i*4 + h
  int bt = rb / 8;
  int t = bt % T;
  int b = bt / T;
  int i = gi >> 2, h = gi & 3;
  int d = threadIdx.x;
  int c = i * 512 + h * 128 + d;
  const float* wc = w + (size_t)c * KSZ;
  float acc = 0.f;
#pragma unroll
  for (int kk = 0; kk < KSZ; kk++) {
    int tt = t - (KSZ - 1) + kk;
    if (tt >= 0) acc = fmaf(x[(size_t)(b * T + tt) * ldx + c], wc[kk], acc);
  }
  float val = acc / (1.f + expf(-acc));
  float ss = wave_sum(val * val);
  __shared__ float sred[2];
  if ((threadIdx.x & 63) == 0) sred[threadIdx.x >> 6] = ss;
  __syncthreads();
  val *= rsqrtf(sred[0] + sred[1] + 1e-6f);
  y[((size_t)(b * T + t) * 4 + h) * 256 + (d >> 1) * 4 + (d & 1) + i * 2] = val;
}

// ---------------- conv+SiLU for v -> pair-major layout
__global__ __launch_bounds__(256) void conv_v(const float* __restrict__ x, int ldx,
                                              const float* __restrict__ w,
                                              float* __restrict__ y, int T) {
  int rb = blockIdx.x;
  int gi = rb % 8;  // i*4 + h
  int bt = rb / 8;
  int t = bt % T;
  int b = bt / T;
  int i = gi >> 2, h = gi & 3;
  int d = threadIdx.x;
  int c = i * 1024 + h * 256 + d;
  const float* wc = w + (size_t)c * KSZ;
  float acc = 0.f;
#pragma unroll
  for (int kk = 0; kk < KSZ; kk++) {
    int tt = t - (KSZ - 1) + kk;
    if (tt >= 0) acc = fmaf(x[(size_t)(b * T + tt) * ldx + c], wc[kk], acc);
  }
  float val = acc / (1.f + expf(-acc));
  y[((size_t)(b * 512 + (t >> 1)) * 4 + h) * 1024 + d * 4 + (t & 1) * 2 + i] = val;
}

// ---------------- 2-step coefficient records (24 floats per (b,tp,h))
__global__ __launch_bounds__(256) void cross_dots2(const float* __restrict__ kbuf2,
                                                   const float* __restrict__ qbuf2,
                                                   const float* __restrict__ beta,
                                                   const float* __restrict__ gam,
                                                   float* __restrict__ rec) {
  int idx = blockIdx.x * 4 + (threadIdx.x >> 6);  // (b*512+tp)*4 + h
  int lane = threadIdx.x & 63;
  int h = idx & 3, tp = (idx >> 2) & 511, b = idx >> 11;
  int t = 2 * tp;
  const float4 kA = *(const float4*)&kbuf2[((size_t)(b * 1024 + t) * 4 + h) * 256 + lane * 4];
  const float4 kB = *(const float4*)&kbuf2[((size_t)(b * 1024 + t + 1) * 4 + h) * 256 + lane * 4];
  const float4 qv = *(const float4*)&qbuf2[(size_t)idx * 256 + lane * 4];
  float d[12];
  d[0] = kA.z * kA.x + kA.w * kA.y;   // d10
  d[1] = kB.x * kA.x + kB.y * kA.y;   // d20
  d[2] = kB.x * kA.z + kB.y * kA.w;   // d21
  d[3] = kB.z * kA.x + kB.w * kA.y;   // d30
  d[4] = kB.z * kA.z + kB.w * kA.w;   // d31
  d[5] = kB.z * kB.x + kB.w * kB.y;   // d32
  d[6] = qv.x * kA.x + qv.y * kA.y;   // e00
  d[7] = qv.x * kA.z + qv.y * kA.w;   // e01
  d[8] = qv.z * kA.x + qv.w * kA.y;   // e10
  d[9] = qv.z * kA.z + qv.w * kA.w;   // e11
  d[10] = qv.z * kB.x + qv.w * kB.y;  // e12
  d[11] = qv.z * kB.z + qv.w * kB.w;  // e13
  dpp_reduce(d);
  int bt = b * 1024 + t;
  float b0 = beta[(size_t)(bt * 2 + 0) * 4 + h];
  float b1 = beta[(size_t)(bt * 2 + 1) * 4 + h];
  float b2 = beta[(size_t)(bt * 2 + 2) * 4 + h];
  float b3 = beta[(size_t)(bt * 2 + 3) * 4 + h];
  float gt = gam[(size_t)bt * 4 + h];
  float gt1 = gam[(size_t)(bt + 1) * 4 + h];
  if (lane == 0) {
    float G2 = gt * gt1;
    float4* rp = (float4*)&rec[(size_t)idx * 24];
    rp[0] = {b0 * gt, b1 * gt, b1 * d[0], gt};
    rp[1] = {b2 * G2, b2 * gt1 * d[1], b2 * gt1 * d[2], gt1};
    rp[2] = {b3 * G2, b3 * gt1 * d[3], b3 * gt1 * d[4], b3 * d[5]};
    rp[3] = {d[6], d[7], G2, b0};
    rp[4] = {gt1 * d[8], gt1 * d[9], d[10], d[11]};
    rp[5] = {b1, b2, b3, 0.f};
  }
}

// ---------------- 2-step batched gated-delta scan, one wave per (b,h,dv-column)
__global__ __launch_bounds__(256, 2) void scan2(const float4* __restrict__ kb,
                                                const float4* __restrict__ qb,
                                                const float4* __restrict__ vb,
                                                const float4* __restrict__ rb,
                                                float* __restrict__ o) {
  const int lane = threadIdx.x & 63;
  const int wave = __builtin_amdgcn_readfirstlane(threadIdx.x >> 6);
  const int bh = blockIdx.x & 7;   // XCD-local
  const int cb = blockIdx.x >> 3;
  const int b = bh >> 2, h = bh & 3;
  const int col = cb * 4 + wave;

  // rolling pointers (float4 units); kp biased +128 so kA=-128, kB=+128 (±2048B offsets)
  const float4* kp = kb + ((size_t)(b * 1024) * 4 + h) * 64 + lane + 128;
  const float4* qp = qb + ((size_t)(b * 512) * 4 + h) * 64 + lane;
  const float4* vp = vb + ((size_t)(b * 512) * 4 + h) * 256 + col;
  const float4* rp = rb + ((size_t)(b * 512) * 4 + h) * 6;
  float* op = o + (size_t)(b * 1024) * NTOT + h * 256 + col;

  float sx = 0.f, sy = 0.f;

  float4 AkA, AkB, Aqv, Avv, AR0, AR1, AR2, AR3, AR4, AR5;
  float4 BkA, BkB, Bqv, Bvv, BR0, BR1, BR2, BR3, BR4, BR5;

#define LOADQ(P) { \
    P##kA = kp[-128]; \
    P##kB = kp[128]; \
    P##qv = qp[0]; \
    P##vv = vp[0]; \
    P##R0 = rp[0]; \
    P##R1 = rp[1]; \
    P##R2 = rp[2]; \
    P##R3 = rp[3]; \
    P##R4 = rp[4]; \
    P##R5 = rp[5]; \
    kp += 512; qp += 256; vp += 1024; rp += 24; \
    __builtin_amdgcn_sched_barrier(0); }

#define STEPQ(P) { \
    float r[6]; \
    r[0] = P##kA.x * sx + P##kA.y * sy; \
    r[1] = P##kA.z * sx + P##kA.w * sy; \
    r[2] = P##kB.x * sx + P##kB.y * sy; \
    r[3] = P##kB.z * sx + P##kB.w * sy; \
    r[4] = P##qv.x * sx + P##qv.y * sy; \
    r[5] = P##qv.z * sx + P##qv.w * sy; \
    dpp_reduce(r); \
    float c0 = fmaf(-P##R0.x, r[0], P##R3.w * P##vv.x); \
    float c1 = fmaf(-P##R0.z, c0, fmaf(-P##R0.y, r[1], P##R5.x * P##vv.y)); \
    float c2 = fmaf(-P##R1.z, c1, fmaf(-P##R1.y, c0, fmaf(-P##R1.x, r[2], P##R5.y * P##vv.z))); \
    float c3 = fmaf(-P##R2.w, c2, fmaf(-P##R2.z, c1, fmaf(-P##R2.y, c0, \
               fmaf(-P##R2.x, r[3], P##R5.z * P##vv.w)))); \
    float ot = fmaf(P##R3.y, c1, fmaf(P##R3.x, c0, P##R0.w * r[4])); \
    float ot1 = fmaf(P##R4.w, c3, fmaf(P##R4.z, c2, fmaf(P##R4.y, c1, \
                fmaf(P##R4.x, c0, P##R3.z * r[5])))); \
    float g0 = P##R1.w * c0, g1 = P##R1.w * c1; \
    sx = fmaf(c3, P##kB.z, fmaf(c2, P##kB.x, fmaf(g1, P##kA.z, fmaf(g0, P##kA.x, P##R3.z * sx)))); \
    sy = fmaf(c3, P##kB.w, fmaf(c2, P##kB.y, fmaf(g1, P##kA.w, fmaf(g0, P##kA.y, P##R3.z * sy)))); \
    if (lane == 0) { op[0] = ot; op[NTOT] = ot1; } \
    op += 2 * NTOT; }

  LOADQ(A)
  LOADQ(B)
  for (int it = 0; it < 255; ++it) {
    STEPQ(A) LOADQ(A)
    STEPQ(B) LOADQ(B)
  }
  STEPQ(A)
  STEPQ(B)
#undef LOADQ
#undef STEPQ
}

// ---------------- RMSNorm(o) * w * SiLU(gate); writes dense bf16 [M][1024]
__global__ __launch_bounds__(256) void post_norm_gate(const float* __restrict__ o,
                                                      const float* __restrict__ gate,
                                                      const float* __restrict__ w,
                                                      ushort* __restrict__ obf) {
  int rb = blockIdx.x;
  int bt = rb >> 2, h = rb & 3;
  int tid = threadIdx.x;
  size_t ob = (size_t)bt * NTOT + h * 256 + tid;
  float ov = o[ob];
  float ss = wave_sum(ov * ov);
  __shared__ float sred[4];
  if ((tid & 63) == 0) sred[tid >> 6] = ss;
  __syncthreads();
  float tot = sred[0] + sred[1] + sred[2] + sred[3];
  float rms = rsqrtf(tot * (1.f / 256.f) + 1e-5f);
  float gt = gate[(size_t)bt * NTOT + h * 256 + tid];
  float val = ov * rms * w[tid] * (gt / (1.f + expf(-gt)));
  obf[(size_t)bt * HID + h * 256 + tid] = f2bf(val);
}

extern "C" void kernel_launch(void* const* d_in, const int* in_sizes, int n_in,
                              void* d_out, int out_size, void* d_ws, size_t ws_size,
                              hipStream_t stream) {
  const float* hs      = (const float*)d_in[0];
  const float* Wq      = (const float*)d_in[1];
  const float* Wk      = (const float*)d_in[2];
  const float* Wv      = (const float*)d_in[3];
  const float* Wb      = (const float*)d_in[4];
  const float* Wa      = (const float*)d_in[5];
  const float* Wg      = (const float*)d_in[6];
  const float* Wo      = (const float*)d_in[7];
  const float* A_log   = (const float*)d_in[8];
  const float* dt_bias = (const float*)d_in[9];
  const float* wq_conv = (const float*)d_in[10];
  const float* wk_conv = (const float*)d_in[11];
  const float* wv_conv = (const float*)d_in[12];
  const float* o_w     = (const float*)d_in[13];
  float* out = (float*)d_out;

  const int B = 2, T = 1024, M = B * T;

  float* ws    = (float*)d_ws;
  float* qkvg  = ws;                          // M*4608 fp32; cols 0..1023 get o; 3584+ gate
  float* kbuf  = qkvg + (size_t)M * NTOT;     // M*1024 (k interleaved)
  float* vbuf  = kbuf + (size_t)M * 1024;     // M*2048 (v pair-major)
  float* betab = vbuf + (size_t)M * 2048;     // M*8
  float* gb    = betab + (size_t)M * 8;       // M*4 (gamma)
  float* recb  = gb + (size_t)M * 4;          // 4096*24 floats
  float* qbuf  = out;                         // M*512 scratch (q pair-interleaved)

  // time-disjoint bf16 aliases in kbuf/vbuf regions:
  ushort* bqkvgT = (ushort*)kbuf;
  ushort* hsb    = (ushort*)(vbuf + (size_t)524288);  // vbuf + 2MB
  ushort* woT = (ushort*)kbuf;
  ushort* obf = (ushort*)vbuf;

  // casts + projections
  cast_hs<<<(M * HID / 4) / 256, 256, 0, stream>>>(hs, hsb);
  tr_pack<<<dim3(NTOT / 32, HID / 32), 256, 0, stream>>>(Wq, Wk, Wv, Wg, bqkvgT);
  gemm_bf16<<<dim3(NTOT / 128, M / 128), 256, 0, stream>>>(hsb, bqkvgT, qkvg, HID, NTOT);
  proj_bg<<<M, 256, 0, stream>>>(hs, Wb, Wa, A_log, dt_bias, betab, gb);
  // conv + SiLU (+ l2norm q,k) into scan-friendly layouts
  conv_q<<<M * 4, 128, 0, stream>>>(qkvg + 0, NTOT, wq_conv, qbuf, T);
  conv_k<<<M * 8, 128, 0, stream>>>(qkvg + 512, NTOT, wk_conv, kbuf, T);
  conv_v<<<M * 8, 256, 0, stream>>>(qkvg + 1536, NTOT, wv_conv, vbuf, T);
  // 2-step coefficient records
  cross_dots2<<<M * H / 8, 256, 0, stream>>>(kbuf, qbuf, betab, gb, recb);
  // batched scan -> o into qkvg cols 0..1023
  scan2<<<512, 256, 0, stream>>>((const float4*)kbuf, (const float4*)qbuf,
                                 (const float4*)vbuf, (const float4*)recb, qkvg);
  // epilogue + output projection
  post_norm_gate<<<M * H, 256, 0, stream>>>(qkvg, qkvg + 3584, o_w, obf);
  tr_one<<<dim3(HID / 32, HID / 32), 256, 0, stream>>>(Wo, woT, HID);
  gemm_bf16<<<dim3(HID / 128, M / 128), 256, 0, stream>>>(obf, woT, out, HID, HID);
}

// Round 20
// 394.707 us; speedup vs baseline: 1.3402x; 1.0630x over previous
//
#include <hip/hip_runtime.h>
#include <cstdint>
#include <cstddef>

#define H 4
#define DK 128
#define DV 256
#define NH 2
#define HID 1024
#define KSZ 4
#define NTOT 4608  // packed projection width: 512 q | 1024 k | 2048 v | 1024 g

typedef __bf16 bfx8 __attribute__((ext_vector_type(8)));
typedef float f32x4 __attribute__((ext_vector_type(4)));

typedef __attribute__((address_space(1))) const void GVOID;
typedef __attribute__((address_space(3))) void LVOID;
#define GLL(g, l) __builtin_amdgcn_global_load_lds((GVOID*)(g), (LVOID*)(l), 16, 0, 0)

__device__ __forceinline__ float wave_sum(float x) {
#pragma unroll
  for (int off = 1; off < 64; off <<= 1) x += __shfl_xor(x, off, 64);
  return x;
}

__device__ __forceinline__ ushort f2bf(float x) {
  uint u = __float_as_uint(x);
  return (ushort)((u + 0x7fffu + ((u >> 16) & 1u)) >> 16);
}

#define DPP_ADD(x, ctrl) \
  x += __int_as_float(__builtin_amdgcn_update_dpp(0, __float_as_int(x), ctrl, 0xf, 0xf, true))

// N independent full-wave64 sums (6-stage); results uniform via readlane(63)
template <int N>
__device__ __forceinline__ void dpp_reduce(float (&d)[N]) {
#pragma unroll
  for (int i = 0; i < N; i++) DPP_ADD(d[i], 0x111);
#pragma unroll
  for (int i = 0; i < N; i++) DPP_ADD(d[i], 0x112);
#pragma unroll
  for (int i = 0; i < N; i++) DPP_ADD(d[i], 0x114);
#pragma unroll
  for (int i = 0; i < N; i++) DPP_ADD(d[i], 0x118);
#pragma unroll
  for (int i = 0; i < N; i++) DPP_ADD(d[i], 0x142);
#pragma unroll
  for (int i = 0; i < N; i++) DPP_ADD(d[i], 0x143);
#pragma unroll
  for (int i = 0; i < N; i++)
    d[i] = __int_as_float(__builtin_amdgcn_readlane(__float_as_int(d[i]), 63));
}

// ---------------- fp32 -> bf16 cast
__global__ __launch_bounds__(256) void cast_hs(const float* __restrict__ src,
                                               ushort* __restrict__ dst) {
  int i = blockIdx.x * 256 + threadIdx.x;
  float4 v = ((const float4*)src)[i];
  ushort4 o = {f2bf(v.x), f2bf(v.y), f2bf(v.z), f2bf(v.w)};
  ((ushort4*)dst)[i] = o;
}

// ---------------- transpose+cast packed weights
__global__ __launch_bounds__(256) void tr_pack(const float* __restrict__ Wq,
                                               const float* __restrict__ Wk,
                                               const float* __restrict__ Wv,
                                               const float* __restrict__ Wg,
                                               ushort* __restrict__ Bt) {
  __shared__ float tile[32][33];
  int n0 = blockIdx.x * 32, k0 = blockIdx.y * 32;
  const float* src;
  int ld, nb;
  if (n0 < 512)       { src = Wq; ld = 512;  nb = n0; }
  else if (n0 < 1536) { src = Wk; ld = 1024; nb = n0 - 512; }
  else if (n0 < 3584) { src = Wv; ld = 2048; nb = n0 - 1536; }
  else                { src = Wg; ld = 1024; nb = n0 - 3584; }
  int tx = threadIdx.x & 31, ty = threadIdx.x >> 5;
#pragma unroll
  for (int i = 0; i < 4; i++)
    tile[ty + i * 8][tx] = src[(size_t)(k0 + ty + i * 8) * ld + nb + tx];
  __syncthreads();
#pragma unroll
  for (int i = 0; i < 4; i++)
    Bt[(size_t)(n0 + ty + i * 8) * 1024 + k0 + tx] = f2bf(tile[tx][ty + i * 8]);
}

__global__ __launch_bounds__(256) void tr_one(const float* __restrict__ W,
                                              ushort* __restrict__ Bt, int N) {
  __shared__ float tile[32][33];
  int n0 = blockIdx.x * 32, k0 = blockIdx.y * 32;
  int tx = threadIdx.x & 31, ty = threadIdx.x >> 5;
#pragma unroll
  for (int i = 0; i < 4; i++)
    tile[ty + i * 8][tx] = W[(size_t)(k0 + ty + i * 8) * N + n0 + tx];
  __syncthreads();
#pragma unroll
  for (int i = 0; i < 4; i++)
    Bt[(size_t)(n0 + ty + i * 8) * 1024 + k0 + tx] = f2bf(tile[tx][ty + i * 8]);
}

// ---------------- bf16 MFMA GEMM with global_load_lds staging (m97 recipe)
__global__ __launch_bounds__(256) void gemm_bf16(const ushort* __restrict__ A,
                                                 const ushort* __restrict__ Bt,
                                                 float* __restrict__ C,
                                                 int K, int ldc) {
  __shared__ __align__(16) ushort As[128][32];
  __shared__ __align__(16) ushort Bs[128][32];
  const int tid = threadIdx.x;
  const int lane = tid & 63, wave = tid >> 6;
  const int wr = wave >> 1, wc = wave & 1;
  const int row0 = blockIdx.y * 128, col0 = blockIdx.x * 128;

  const int ra = wave * 32 + (lane >> 2);
  const int rb = ra + 16;
  const int kc = (lane & 3) * 8;
  const ushort* pa0 = A + (size_t)(row0 + ra) * K + kc;
  const ushort* pa1 = A + (size_t)(row0 + rb) * K + kc;
  const ushort* pb0 = Bt + (size_t)(col0 + ra) * K + kc;
  const ushort* pb1 = Bt + (size_t)(col0 + rb) * K + kc;
  ushort* lA0 = &As[wave * 32][0];
  ushort* lA1 = &As[wave * 32 + 16][0];
  ushort* lB0 = &Bs[wave * 32][0];
  ushort* lB1 = &Bs[wave * 32 + 16][0];

  f32x4 acc[4][4];
#pragma unroll
  for (int i = 0; i < 4; i++)
#pragma unroll
    for (int j = 0; j < 4; j++) acc[i][j] = {0.f, 0.f, 0.f, 0.f};

  const int lrow = lane & 15, lk = (lane >> 4) * 8;

  for (int k0 = 0; k0 < K; k0 += 32) {
    __syncthreads();
    GLL(pa0, lA0);
    GLL(pa1, lA1);
    GLL(pb0, lB0);
    GLL(pb1, lB1);
    pa0 += 32; pa1 += 32; pb0 += 32; pb1 += 32;
    __syncthreads();
    bfx8 af[4], bf[4];
#pragma unroll
    for (int mf = 0; mf < 4; mf++)
      af[mf] = *(const bfx8*)&As[wr * 64 + mf * 16 + lrow][lk];
#pragma unroll
    for (int nf = 0; nf < 4; nf++)
      bf[nf] = *(const bfx8*)&Bs[wc * 64 + nf * 16 + lrow][lk];
#pragma unroll
    for (int mf = 0; mf < 4; mf++)
#pragma unroll
      for (int nf = 0; nf < 4; nf++)
        acc[mf][nf] = __builtin_amdgcn_mfma_f32_16x16x32_bf16(af[mf], bf[nf], acc[mf][nf], 0, 0, 0);
  }
  const int crow = (lane >> 4) * 4, ccol = lane & 15;
#pragma unroll
  for (int mf = 0; mf < 4; mf++)
#pragma unroll
    for (int nf = 0; nf < 4; nf++)
#pragma unroll
      for (int rr = 0; rr < 4; rr++)
        C[(size_t)(row0 + wr * 64 + mf * 16 + crow + rr) * ldc + col0 + wc * 64 + nf * 16 + ccol] =
            acc[mf][nf][rr];
}

// ---------------- beta / gamma tiny projections (gamma = exp(g))
__global__ __launch_bounds__(256) void proj_bg(const float* __restrict__ hs,
                                               const float* __restrict__ Wb,
                                               const float* __restrict__ Wa,
                                               const float* __restrict__ A_log,
                                               const float* __restrict__ dt_bias,
                                               float* __restrict__ beta,
                                               float* __restrict__ g) {
  int row = blockIdx.x;
  int lane = threadIdx.x & 63;
  int wave = threadIdx.x >> 6;
  const float* x = hs + (size_t)row * HID;
  for (int out = wave; out < 12; out += 4) {
    float sum = 0.f;
    if (out < 8) {
      for (int k = lane; k < HID; k += 64) sum = fmaf(x[k], Wb[(size_t)k * 8 + out], sum);
    } else {
      int c = out - 8;
      for (int k = lane; k < HID; k += 64) sum = fmaf(x[k], Wa[(size_t)k * 4 + c], sum);
    }
    sum = wave_sum(sum);
    if (lane == 0) {
      if (out < 8) {
        beta[(size_t)row * 8 + out] = 2.f / (1.f + expf(-sum));
      } else {
        int h = out - 8;
        float xx = sum + dt_bias[h];
        float sp = (xx > 20.f) ? xx : log1pf(expf(xx));
        g[(size_t)row * 4 + h] = expf(-expf(A_log[h]) * sp);  // gamma
      }
    }
  }
}

// ---------------- fused conv+SiLU(+l2norm) for q,k,v in ONE kernel.
// One block per (b, 16-t chunk, 256-ch group): input window read ONCE (19 rows)
// vs 4x re-read in the per-timestep kernels. Region/layouts identical to the
// verified conv_q/conv_k/conv_v (fma tap order + norm tree bit-identical).
__global__ __launch_bounds__(256) void conv_all(const float* __restrict__ x,
                                                const float* __restrict__ wqc,
                                                const float* __restrict__ wkc,
                                                const float* __restrict__ wvc,
                                                float* __restrict__ yq,
                                                float* __restrict__ yk,
                                                float* __restrict__ yv, int T) {
  int blk = blockIdx.x;
  int cg = blk % 14;
  int tc = (blk / 14) % 64;
  int b  = blk / (14 * 64);
  int tid = threadIdx.x;
  int c = cg * 256 + tid;       // qkvg conv column (0..3583)
  int t0 = tc * 16;
  const int lane = tid & 63, wav = tid >> 6;

  int region, h, d, ii = 0;
  const float* wp;
  if (c < 512)       { region = 0; h = c >> 7; d = c & 127; wp = wqc + (size_t)c * 4; }
  else if (c < 1536) { int ck = c - 512;  region = 1; ii = ck >> 9;  h = (ck >> 7) & 3; d = ck & 127; wp = wkc + (size_t)ck * 4; }
  else               { int cv = c - 1536; region = 2; ii = cv >> 10; h = (cv >> 8) & 3; d = cv & 255; wp = wvc + (size_t)cv * 4; }
  float4 wcv = *(const float4*)wp;

  const float* xp = x + (size_t)(b * T) * NTOT + c;
#define XLD(t) (((t) >= 0) ? xp[(size_t)(t) * NTOT] : 0.f)
  float w0 = XLD(t0 - 3), w1 = XLD(t0 - 2), w2 = XLD(t0 - 1);

  __shared__ float sred[4];

  for (int tt = 0; tt < 16; ++tt) {
    int t = t0 + tt;
    float w3 = XLD(t);
    float acc = 0.f;
    acc = fmaf(w0, wcv.x, acc);
    acc = fmaf(w1, wcv.y, acc);
    acc = fmaf(w2, wcv.z, acc);
    acc = fmaf(w3, wcv.w, acc);
    float val = acc / (1.f + expf(-acc));
    if (region != 2) {  // uniform per block (q/k groups are 256-ch aligned)
      float ss = wave_sum(val * val);
      if (lane == 0) sred[wav] = ss;
      __syncthreads();
      float tot = sred[(tid >> 7) * 2] + sred[(tid >> 7) * 2 + 1];
      __syncthreads();
      val *= rsqrtf(tot + 1e-6f);
    }
    if (region == 0)
      yq[((size_t)(b * 512 + (t >> 1)) * 4 + h) * 256 + (d >> 1) * 4 + (d & 1) + (t & 1) * 2] = val;
    else if (region == 1)
      yk[((size_t)(b * T + t) * 4 + h) * 256 + (d >> 1) * 4 + (d & 1) + ii * 2] = val;
    else
      yv[((size_t)(b * 512 + (t >> 1)) * 4 + h) * 1024 + d * 4 + (t & 1) * 2 + ii] = val;
    w0 = w1; w1 = w2; w2 = w3;
  }
#undef XLD
}

// ---------------- 2-step coefficient records (24 floats per (b,tp,h))
__global__ __launch_bounds__(256) void cross_dots2(const float* __restrict__ kbuf2,
                                                   const float* __restrict__ qbuf2,
                                                   const float* __restrict__ beta,
                                                   const float* __restrict__ gam,
                                                   float* __restrict__ rec) {
  int idx = blockIdx.x * 4 + (threadIdx.x >> 6);  // (b*512+tp)*4 + h
  int lane = threadIdx.x & 63;
  int h = idx & 3, tp = (idx >> 2) & 511, b = idx >> 11;
  int t = 2 * tp;
  const float4 kA = *(const float4*)&kbuf2[((size_t)(b * 1024 + t) * 4 + h) * 256 + lane * 4];
  const float4 kB = *(const float4*)&kbuf2[((size_t)(b * 1024 + t + 1) * 4 + h) * 256 + lane * 4];
  const float4 qv = *(const float4*)&qbuf2[(size_t)idx * 256 + lane * 4];
  float d[12];
  d[0] = kA.z * kA.x + kA.w * kA.y;   // d10
  d[1] = kB.x * kA.x + kB.y * kA.y;   // d20
  d[2] = kB.x * kA.z + kB.y * kA.w;   // d21
  d[3] = kB.z * kA.x + kB.w * kA.y;   // d30
  d[4] = kB.z * kA.z + kB.w * kA.w;   // d31
  d[5] = kB.z * kB.x + kB.w * kB.y;   // d32
  d[6] = qv.x * kA.x + qv.y * kA.y;   // e00
  d[7] = qv.x * kA.z + qv.y * kA.w;   // e01
  d[8] = qv.z * kA.x + qv.w * kA.y;   // e10
  d[9] = qv.z * kA.z + qv.w * kA.w;   // e11
  d[10] = qv.z * kB.x + qv.w * kB.y;  // e12
  d[11] = qv.z * kB.z + qv.w * kB.w;  // e13
  dpp_reduce(d);
  int bt = b * 1024 + t;
  float b0 = beta[(size_t)(bt * 2 + 0) * 4 + h];
  float b1 = beta[(size_t)(bt * 2 + 1) * 4 + h];
  float b2 = beta[(size_t)(bt * 2 + 2) * 4 + h];
  float b3 = beta[(size_t)(bt * 2 + 3) * 4 + h];
  float gt = gam[(size_t)bt * 4 + h];
  float gt1 = gam[(size_t)(bt + 1) * 4 + h];
  if (lane == 0) {
    float G2 = gt * gt1;
    float4* rp = (float4*)&rec[(size_t)idx * 24];
    rp[0] = {b0 * gt, b1 * gt, b1 * d[0], gt};
    rp[1] = {b2 * G2, b2 * gt1 * d[1], b2 * gt1 * d[2], gt1};
    rp[2] = {b3 * G2, b3 * gt1 * d[3], b3 * gt1 * d[4], b3 * d[5]};
    rp[3] = {d[6], d[7], G2, b0};
    rp[4] = {gt1 * d[8], gt1 * d[9], d[10], d[11]};
    rp[5] = {b1, b2, b3, 0.f};
  }
}

// ---------------- 2-step batched gated-delta scan, one wave per (b,h,dv-column)
__global__ __launch_bounds__(256, 2) void scan2(const float4* __restrict__ kb,
                                                const float4* __restrict__ qb,
                                                const float4* __restrict__ vb,
                                                const float4* __restrict__ rb,
                                                float* __restrict__ o) {
  const int lane = threadIdx.x & 63;
  const int wave = __builtin_amdgcn_readfirstlane(threadIdx.x >> 6);
  const int bh = blockIdx.x & 7;   // XCD-local
  const int cb = blockIdx.x >> 3;
  const int b = bh >> 2, h = bh & 3;
  const int col = cb * 4 + wave;

  const float4* kp = kb + ((size_t)(b * 1024) * 4 + h) * 64 + lane + 128;
  const float4* qp = qb + ((size_t)(b * 512) * 4 + h) * 64 + lane;
  const float4* vp = vb + ((size_t)(b * 512) * 4 + h) * 256 + col;
  const float4* rp = rb + ((size_t)(b * 512) * 4 + h) * 6;
  float* op = o + (size_t)(b * 1024) * NTOT + h * 256 + col;

  float sx = 0.f, sy = 0.f;

  float4 AkA, AkB, Aqv, Avv, AR0, AR1, AR2, AR3, AR4, AR5;
  float4 BkA, BkB, Bqv, Bvv, BR0, BR1, BR2, BR3, BR4, BR5;

#define LOADQ(P) { \
    P##kA = kp[-128]; \
    P##kB = kp[128]; \
    P##qv = qp[0]; \
    P##vv = vp[0]; \
    P##R0 = rp[0]; \
    P##R1 = rp[1]; \
    P##R2 = rp[2]; \
    P##R3 = rp[3]; \
    P##R4 = rp[4]; \
    P##R5 = rp[5]; \
    kp += 512; qp += 256; vp += 1024; rp += 24; \
    __builtin_amdgcn_sched_barrier(0); }

#define STEPQ(P) { \
    float r[6]; \
    r[0] = P##kA.x * sx + P##kA.y * sy; \
    r[1] = P##kA.z * sx + P##kA.w * sy; \
    r[2] = P##kB.x * sx + P##kB.y * sy; \
    r[3] = P##kB.z * sx + P##kB.w * sy; \
    r[4] = P##qv.x * sx + P##qv.y * sy; \
    r[5] = P##qv.z * sx + P##qv.w * sy; \
    dpp_reduce(r); \
    float c0 = fmaf(-P##R0.x, r[0], P##R3.w * P##vv.x); \
    float c1 = fmaf(-P##R0.z, c0, fmaf(-P##R0.y, r[1], P##R5.x * P##vv.y)); \
    float c2 = fmaf(-P##R1.z, c1, fmaf(-P##R1.y, c0, fmaf(-P##R1.x, r[2], P##R5.y * P##vv.z))); \
    float c3 = fmaf(-P##R2.w, c2, fmaf(-P##R2.z, c1, fmaf(-P##R2.y, c0, \
               fmaf(-P##R2.x, r[3], P##R5.z * P##vv.w)))); \
    float ot = fmaf(P##R3.y, c1, fmaf(P##R3.x, c0, P##R0.w * r[4])); \
    float ot1 = fmaf(P##R4.w, c3, fmaf(P##R4.z, c2, fmaf(P##R4.y, c1, \
                fmaf(P##R4.x, c0, P##R3.z * r[5])))); \
    float g0 = P##R1.w * c0, g1 = P##R1.w * c1; \
    sx = fmaf(c3, P##kB.z, fmaf(c2, P##kB.x, fmaf(g1, P##kA.z, fmaf(g0, P##kA.x, P##R3.z * sx)))); \
    sy = fmaf(c3, P##kB.w, fmaf(c2, P##kB.y, fmaf(g1, P##kA.w, fmaf(g0, P##kA.y, P##R3.z * sy)))); \
    if (lane == 0) { op[0] = ot; op[NTOT] = ot1; } \
    op += 2 * NTOT; }

  LOADQ(A)
  LOADQ(B)
  for (int it = 0; it < 255; ++it) {
    STEPQ(A) LOADQ(A)
    STEPQ(B) LOADQ(B)
  }
  STEPQ(A)
  STEPQ(B)
#undef LOADQ
#undef STEPQ
}

// ---------------- RMSNorm(o) * w * SiLU(gate); writes dense bf16 [M][1024]
__global__ __launch_bounds__(256) void post_norm_gate(const float* __restrict__ o,
                                                      const float* __restrict__ gate,
                                                      const float* __restrict__ w,
                                                      ushort* __restrict__ obf) {
  int rb = blockIdx.x;
  int bt = rb >> 2, h = rb & 3;
  int tid = threadIdx.x;
  size_t ob = (size_t)bt * NTOT + h * 256 + tid;
  float ov = o[ob];
  float ss = wave_sum(ov * ov);
  __shared__ float sred[4];
  if ((tid & 63) == 0) sred[tid >> 6] = ss;
  __syncthreads();
  float tot = sred[0] + sred[1] + sred[2] + sred[3];
  float rms = rsqrtf(tot * (1.f / 256.f) + 1e-5f);
  float gt = gate[(size_t)bt * NTOT + h * 256 + tid];
  float val = ov * rms * w[tid] * (gt / (1.f + expf(-gt)));
  obf[(size_t)bt * HID + h * 256 + tid] = f2bf(val);
}

extern "C" void kernel_launch(void* const* d_in, const int* in_sizes, int n_in,
                              void* d_out, int out_size, void* d_ws, size_t ws_size,
                              hipStream_t stream) {
  const float* hs      = (const float*)d_in[0];
  const float* Wq      = (const float*)d_in[1];
  const float* Wk      = (const float*)d_in[2];
  const float* Wv      = (const float*)d_in[3];
  const float* Wb      = (const float*)d_in[4];
  const float* Wa      = (const float*)d_in[5];
  const float* Wg      = (const float*)d_in[6];
  const float* Wo      = (const float*)d_in[7];
  const float* A_log   = (const float*)d_in[8];
  const float* dt_bias = (const float*)d_in[9];
  const float* wq_conv = (const float*)d_in[10];
  const float* wk_conv = (const float*)d_in[11];
  const float* wv_conv = (const float*)d_in[12];
  const float* o_w     = (const float*)d_in[13];
  float* out = (float*)d_out;

  const int B = 2, T = 1024, M = B * T;

  float* ws    = (float*)d_ws;
  float* qkvg  = ws;                          // M*4608 fp32; cols 0..1023 get o; 3584+ gate
  float* kbuf  = qkvg + (size_t)M * NTOT;     // M*1024 (k interleaved)
  float* vbuf  = kbuf + (size_t)M * 1024;     // M*2048 (v pair-major)
  float* betab = vbuf + (size_t)M * 2048;     // M*8
  float* gb    = betab + (size_t)M * 8;       // M*4 (gamma)
  float* recb  = gb + (size_t)M * 4;          // 4096*24 floats
  float* qbuf  = out;                         // M*512 scratch (q pair-interleaved)

  // time-disjoint bf16 aliases in kbuf/vbuf regions:
  ushort* bqkvgT = (ushort*)kbuf;
  ushort* hsb    = (ushort*)(vbuf + (size_t)524288);  // vbuf + 2MB
  ushort* woT = (ushort*)kbuf;
  ushort* obf = (ushort*)vbuf;

  // casts + projections
  cast_hs<<<(M * HID / 4) / 256, 256, 0, stream>>>(hs, hsb);
  tr_pack<<<dim3(NTOT / 32, HID / 32), 256, 0, stream>>>(Wq, Wk, Wv, Wg, bqkvgT);
  gemm_bf16<<<dim3(NTOT / 128, M / 128), 256, 0, stream>>>(hsb, bqkvgT, qkvg, HID, NTOT);
  proj_bg<<<M, 256, 0, stream>>>(hs, Wb, Wa, A_log, dt_bias, betab, gb);
  // fused conv + SiLU (+ l2norm q,k): window read once, all three outputs
  conv_all<<<2 * 64 * 14, 256, 0, stream>>>(qkvg, wq_conv, wk_conv, wv_conv,
                                            qbuf, kbuf, vbuf, T);
  // 2-step coefficient records
  cross_dots2<<<M * H / 8, 256, 0, stream>>>(kbuf, qbuf, betab, gb, recb);
  // batched scan -> o into qkvg cols 0..1023
  scan2<<<512, 256, 0, stream>>>((const float4*)kbuf, (const float4*)qbuf,
                                 (const float4*)vbuf, (const float4*)recb, qkvg);
  // epilogue + output projection
  post_norm_gate<<<M * H, 256, 0, stream>>>(qkvg, qkvg + 3584, o_w, obf);
  tr_one<<<dim3(HID / 32, HID / 32), 256, 0, stream>>>(Wo, woT, HID);
  gemm_bf16<<<dim3(HID / 128, M / 128), 256, 0, stream>>>(obf, woT, out, HID, HID);
}

// Round 21
// 387.169 us; speedup vs baseline: 1.3663x; 1.0195x over previous
//
#include <hip/hip_runtime.h>
#include <cstdint>
#include <cstddef>

#define H 4
#define DK 128
#define DV 256
#define NH 2
#define HID 1024
#define KSZ 4
#define NTOT 4608  // packed projection width: 512 q | 1024 k | 2048 v | 1024 g

typedef __bf16 bfx8 __attribute__((ext_vector_type(8)));
typedef float f32x4 __attribute__((ext_vector_type(4)));

typedef __attribute__((address_space(1))) const void GVOID;
typedef __attribute__((address_space(3))) void LVOID;
#define GLL(g, l) __builtin_amdgcn_global_load_lds((GVOID*)(g), (LVOID*)(l), 16, 0, 0)

__device__ __forceinline__ float wave_sum(float x) {
#pragma unroll
  for (int off = 1; off < 64; off <<= 1) x += __shfl_xor(x, off, 64);
  return x;
}

__device__ __forceinline__ ushort f2bf(float x) {
  uint u = __float_as_uint(x);
  return (ushort)((u + 0x7fffu + ((u >> 16) & 1u)) >> 16);
}

#define DPP_ADD(x, ctrl) \
  x += __int_as_float(__builtin_amdgcn_update_dpp(0, __float_as_int(x), ctrl, 0xf, 0xf, true))

// N independent full-wave64 sums (6-stage); results uniform via readlane(63)
template <int N>
__device__ __forceinline__ void dpp_reduce(float (&d)[N]) {
#pragma unroll
  for (int i = 0; i < N; i++) DPP_ADD(d[i], 0x111);
#pragma unroll
  for (int i = 0; i < N; i++) DPP_ADD(d[i], 0x112);
#pragma unroll
  for (int i = 0; i < N; i++) DPP_ADD(d[i], 0x114);
#pragma unroll
  for (int i = 0; i < N; i++) DPP_ADD(d[i], 0x118);
#pragma unroll
  for (int i = 0; i < N; i++) DPP_ADD(d[i], 0x142);
#pragma unroll
  for (int i = 0; i < N; i++) DPP_ADD(d[i], 0x143);
#pragma unroll
  for (int i = 0; i < N; i++)
    d[i] = __int_as_float(__builtin_amdgcn_readlane(__float_as_int(d[i]), 63));
}

// ---------------- fused front-end: cast_hs | tr_pack | tr_one | proj_bg
// All four are mutually independent 256-thread kernels; block-range dispatch
// removes 3 launch gaps and lets them co-occupy the machine. Bodies verbatim.
__global__ __launch_bounds__(256) void prep(const float* __restrict__ hs,
                                            const float* __restrict__ Wq,
                                            const float* __restrict__ Wk,
                                            const float* __restrict__ Wv,
                                            const float* __restrict__ Wg,
                                            const float* __restrict__ Wo,
                                            const float* __restrict__ Wb,
                                            const float* __restrict__ Wa,
                                            const float* __restrict__ A_log,
                                            const float* __restrict__ dt_bias,
                                            ushort* __restrict__ hsb,
                                            ushort* __restrict__ bqkvgT,
                                            ushort* __restrict__ woT,
                                            float* __restrict__ beta,
                                            float* __restrict__ g) {
  __shared__ float tile[32][33];
  int blk = blockIdx.x;
  int tid = threadIdx.x;
  if (blk < 2048) {
    // ---- cast_hs: fp32 -> bf16, 4 elems/thread
    int i = blk * 256 + tid;
    float4 v = ((const float4*)hs)[i];
    ushort4 o = {f2bf(v.x), f2bf(v.y), f2bf(v.z), f2bf(v.w)};
    ((ushort4*)hsb)[i] = o;
  } else if (blk < 6656) {
    // ---- tr_pack: Bt[4608][1024] bf16, Bt[n][k] = W*[k][n]
    int r = blk - 2048;
    int n0 = (r % 144) * 32, k0 = (r / 144) * 32;
    const float* src;
    int ld, nb;
    if (n0 < 512)       { src = Wq; ld = 512;  nb = n0; }
    else if (n0 < 1536) { src = Wk; ld = 1024; nb = n0 - 512; }
    else if (n0 < 3584) { src = Wv; ld = 2048; nb = n0 - 1536; }
    else                { src = Wg; ld = 1024; nb = n0 - 3584; }
    int tx = tid & 31, ty = tid >> 5;
#pragma unroll
    for (int i = 0; i < 4; i++)
      tile[ty + i * 8][tx] = src[(size_t)(k0 + ty + i * 8) * ld + nb + tx];
    __syncthreads();
#pragma unroll
    for (int i = 0; i < 4; i++)
      bqkvgT[(size_t)(n0 + ty + i * 8) * 1024 + k0 + tx] = f2bf(tile[tx][ty + i * 8]);
  } else if (blk < 7680) {
    // ---- tr_one (Wo): Bt[n][k] = W[k][n]
    int r = blk - 6656;
    int n0 = (r % 32) * 32, k0 = (r / 32) * 32;
    int tx = tid & 31, ty = tid >> 5;
#pragma unroll
    for (int i = 0; i < 4; i++)
      tile[ty + i * 8][tx] = Wo[(size_t)(k0 + ty + i * 8) * HID + n0 + tx];
    __syncthreads();
#pragma unroll
    for (int i = 0; i < 4; i++)
      woT[(size_t)(n0 + ty + i * 8) * 1024 + k0 + tx] = f2bf(tile[tx][ty + i * 8]);
  } else {
    // ---- proj_bg (gamma = exp(g))
    int row = blk - 7680;
    int lane = tid & 63;
    int wave = tid >> 6;
    const float* x = hs + (size_t)row * HID;
    for (int out = wave; out < 12; out += 4) {
      float sum = 0.f;
      if (out < 8) {
        for (int k = lane; k < HID; k += 64) sum = fmaf(x[k], Wb[(size_t)k * 8 + out], sum);
      } else {
        int c = out - 8;
        for (int k = lane; k < HID; k += 64) sum = fmaf(x[k], Wa[(size_t)k * 4 + c], sum);
      }
      sum = wave_sum(sum);
      if (lane == 0) {
        if (out < 8) {
          beta[(size_t)row * 8 + out] = 2.f / (1.f + expf(-sum));
        } else {
          int h = out - 8;
          float xx = sum + dt_bias[h];
          float sp = (xx > 20.f) ? xx : log1pf(expf(xx));
          g[(size_t)row * 4 + h] = expf(-expf(A_log[h]) * sp);  // gamma
        }
      }
    }
  }
}

// ---------------- bf16 MFMA GEMM with global_load_lds staging (m97 recipe)
__global__ __launch_bounds__(256) void gemm_bf16(const ushort* __restrict__ A,
                                                 const ushort* __restrict__ Bt,
                                                 float* __restrict__ C,
                                                 int K, int ldc) {
  __shared__ __align__(16) ushort As[128][32];
  __shared__ __align__(16) ushort Bs[128][32];
  const int tid = threadIdx.x;
  const int lane = tid & 63, wave = tid >> 6;
  const int wr = wave >> 1, wc = wave & 1;
  const int row0 = blockIdx.y * 128, col0 = blockIdx.x * 128;

  const int ra = wave * 32 + (lane >> 2);
  const int rb = ra + 16;
  const int kc = (lane & 3) * 8;
  const ushort* pa0 = A + (size_t)(row0 + ra) * K + kc;
  const ushort* pa1 = A + (size_t)(row0 + rb) * K + kc;
  const ushort* pb0 = Bt + (size_t)(col0 + ra) * K + kc;
  const ushort* pb1 = Bt + (size_t)(col0 + rb) * K + kc;
  ushort* lA0 = &As[wave * 32][0];
  ushort* lA1 = &As[wave * 32 + 16][0];
  ushort* lB0 = &Bs[wave * 32][0];
  ushort* lB1 = &Bs[wave * 32 + 16][0];

  f32x4 acc[4][4];
#pragma unroll
  for (int i = 0; i < 4; i++)
#pragma unroll
    for (int j = 0; j < 4; j++) acc[i][j] = {0.f, 0.f, 0.f, 0.f};

  const int lrow = lane & 15, lk = (lane >> 4) * 8;

  for (int k0 = 0; k0 < K; k0 += 32) {
    __syncthreads();
    GLL(pa0, lA0);
    GLL(pa1, lA1);
    GLL(pb0, lB0);
    GLL(pb1, lB1);
    pa0 += 32; pa1 += 32; pb0 += 32; pb1 += 32;
    __syncthreads();
    bfx8 af[4], bf[4];
#pragma unroll
    for (int mf = 0; mf < 4; mf++)
      af[mf] = *(const bfx8*)&As[wr * 64 + mf * 16 + lrow][lk];
#pragma unroll
    for (int nf = 0; nf < 4; nf++)
      bf[nf] = *(const bfx8*)&Bs[wc * 64 + nf * 16 + lrow][lk];
#pragma unroll
    for (int mf = 0; mf < 4; mf++)
#pragma unroll
      for (int nf = 0; nf < 4; nf++)
        acc[mf][nf] = __builtin_amdgcn_mfma_f32_16x16x32_bf16(af[mf], bf[nf], acc[mf][nf], 0, 0, 0);
  }
  const int crow = (lane >> 4) * 4, ccol = lane & 15;
#pragma unroll
  for (int mf = 0; mf < 4; mf++)
#pragma unroll
    for (int nf = 0; nf < 4; nf++)
#pragma unroll
      for (int rr = 0; rr < 4; rr++)
        C[(size_t)(row0 + wr * 64 + mf * 16 + crow + rr) * ldc + col0 + wc * 64 + nf * 16 + ccol] =
            acc[mf][nf][rr];
}

// ---------------- fused conv+SiLU(+l2norm) for q,k,v (window read once)
__global__ __launch_bounds__(256) void conv_all(const float* __restrict__ x,
                                                const float* __restrict__ wqc,
                                                const float* __restrict__ wkc,
                                                const float* __restrict__ wvc,
                                                float* __restrict__ yq,
                                                float* __restrict__ yk,
                                                float* __restrict__ yv, int T) {
  int blk = blockIdx.x;
  int cg = blk % 14;
  int tc = (blk / 14) % 64;
  int b  = blk / (14 * 64);
  int tid = threadIdx.x;
  int c = cg * 256 + tid;       // qkvg conv column (0..3583)
  int t0 = tc * 16;
  const int lane = tid & 63, wav = tid >> 6;

  int region, h, d, ii = 0;
  const float* wp;
  if (c < 512)       { region = 0; h = c >> 7; d = c & 127; wp = wqc + (size_t)c * 4; }
  else if (c < 1536) { int ck = c - 512;  region = 1; ii = ck >> 9;  h = (ck >> 7) & 3; d = ck & 127; wp = wkc + (size_t)ck * 4; }
  else               { int cv = c - 1536; region = 2; ii = cv >> 10; h = (cv >> 8) & 3; d = cv & 255; wp = wvc + (size_t)cv * 4; }
  float4 wcv = *(const float4*)wp;

  const float* xp = x + (size_t)(b * T) * NTOT + c;
#define XLD(t) (((t) >= 0) ? xp[(size_t)(t) * NTOT] : 0.f)
  float w0 = XLD(t0 - 3), w1 = XLD(t0 - 2), w2 = XLD(t0 - 1);

  __shared__ float sred[4];

  for (int tt = 0; tt < 16; ++tt) {
    int t = t0 + tt;
    float w3 = XLD(t);
    float acc = 0.f;
    acc = fmaf(w0, wcv.x, acc);
    acc = fmaf(w1, wcv.y, acc);
    acc = fmaf(w2, wcv.z, acc);
    acc = fmaf(w3, wcv.w, acc);
    float val = acc / (1.f + expf(-acc));
    if (region != 2) {
      float ss = wave_sum(val * val);
      if (lane == 0) sred[wav] = ss;
      __syncthreads();
      float tot = sred[(tid >> 7) * 2] + sred[(tid >> 7) * 2 + 1];
      __syncthreads();
      val *= rsqrtf(tot + 1e-6f);
    }
    if (region == 0)
      yq[((size_t)(b * 512 + (t >> 1)) * 4 + h) * 256 + (d >> 1) * 4 + (d & 1) + (t & 1) * 2] = val;
    else if (region == 1)
      yk[((size_t)(b * T + t) * 4 + h) * 256 + (d >> 1) * 4 + (d & 1) + ii * 2] = val;
    else
      yv[((size_t)(b * 512 + (t >> 1)) * 4 + h) * 1024 + d * 4 + (t & 1) * 2 + ii] = val;
    w0 = w1; w1 = w2; w2 = w3;
  }
#undef XLD
}

// ---------------- 2-step coefficient records (24 floats per (b,tp,h))
__global__ __launch_bounds__(256) void cross_dots2(const float* __restrict__ kbuf2,
                                                   const float* __restrict__ qbuf2,
                                                   const float* __restrict__ beta,
                                                   const float* __restrict__ gam,
                                                   float* __restrict__ rec) {
  int idx = blockIdx.x * 4 + (threadIdx.x >> 6);  // (b*512+tp)*4 + h
  int lane = threadIdx.x & 63;
  int h = idx & 3, tp = (idx >> 2) & 511, b = idx >> 11;
  int t = 2 * tp;
  const float4 kA = *(const float4*)&kbuf2[((size_t)(b * 1024 + t) * 4 + h) * 256 + lane * 4];
  const float4 kB = *(const float4*)&kbuf2[((size_t)(b * 1024 + t + 1) * 4 + h) * 256 + lane * 4];
  const float4 qv = *(const float4*)&qbuf2[(size_t)idx * 256 + lane * 4];
  float d[12];
  d[0] = kA.z * kA.x + kA.w * kA.y;   // d10
  d[1] = kB.x * kA.x + kB.y * kA.y;   // d20
  d[2] = kB.x * kA.z + kB.y * kA.w;   // d21
  d[3] = kB.z * kA.x + kB.w * kA.y;   // d30
  d[4] = kB.z * kA.z + kB.w * kA.w;   // d31
  d[5] = kB.z * kB.x + kB.w * kB.y;   // d32
  d[6] = qv.x * kA.x + qv.y * kA.y;   // e00
  d[7] = qv.x * kA.z + qv.y * kA.w;   // e01
  d[8] = qv.z * kA.x + qv.w * kA.y;   // e10
  d[9] = qv.z * kA.z + qv.w * kA.w;   // e11
  d[10] = qv.z * kB.x + qv.w * kB.y;  // e12
  d[11] = qv.z * kB.z + qv.w * kB.w;  // e13
  dpp_reduce(d);
  int bt = b * 1024 + t;
  float b0 = beta[(size_t)(bt * 2 + 0) * 4 + h];
  float b1 = beta[(size_t)(bt * 2 + 1) * 4 + h];
  float b2 = beta[(size_t)(bt * 2 + 2) * 4 + h];
  float b3 = beta[(size_t)(bt * 2 + 3) * 4 + h];
  float gt = gam[(size_t)bt * 4 + h];
  float gt1 = gam[(size_t)(bt + 1) * 4 + h];
  if (lane == 0) {
    float G2 = gt * gt1;
    float4* rp = (float4*)&rec[(size_t)idx * 24];
    rp[0] = {b0 * gt, b1 * gt, b1 * d[0], gt};
    rp[1] = {b2 * G2, b2 * gt1 * d[1], b2 * gt1 * d[2], gt1};
    rp[2] = {b3 * G2, b3 * gt1 * d[3], b3 * gt1 * d[4], b3 * d[5]};
    rp[3] = {d[6], d[7], G2, b0};
    rp[4] = {gt1 * d[8], gt1 * d[9], d[10], d[11]};
    rp[5] = {b1, b2, b3, 0.f};
  }
}

// ---------------- 2-step batched gated-delta scan, one wave per (b,h,dv-column)
__global__ __launch_bounds__(256, 2) void scan2(const float4* __restrict__ kb,
                                                const float4* __restrict__ qb,
                                                const float4* __restrict__ vb,
                                                const float4* __restrict__ rb,
                                                float* __restrict__ o) {
  const int lane = threadIdx.x & 63;
  const int wave = __builtin_amdgcn_readfirstlane(threadIdx.x >> 6);
  const int bh = blockIdx.x & 7;   // XCD-local
  const int cb = blockIdx.x >> 3;
  const int b = bh >> 2, h = bh & 3;
  const int col = cb * 4 + wave;

  const float4* kp = kb + ((size_t)(b * 1024) * 4 + h) * 64 + lane + 128;
  const float4* qp = qb + ((size_t)(b * 512) * 4 + h) * 64 + lane;
  const float4* vp = vb + ((size_t)(b * 512) * 4 + h) * 256 + col;
  const float4* rp = rb + ((size_t)(b * 512) * 4 + h) * 6;
  float* op = o + (size_t)(b * 1024) * NTOT + h * 256 + col;

  float sx = 0.f, sy = 0.f;

  float4 AkA, AkB, Aqv, Avv, AR0, AR1, AR2, AR3, AR4, AR5;
  float4 BkA, BkB, Bqv, Bvv, BR0, BR1, BR2, BR3, BR4, BR5;

#define LOADQ(P) { \
    P##kA = kp[-128]; \
    P##kB = kp[128]; \
    P##qv = qp[0]; \
    P##vv = vp[0]; \
    P##R0 = rp[0]; \
    P##R1 = rp[1]; \
    P##R2 = rp[2]; \
    P##R3 = rp[3]; \
    P##R4 = rp[4]; \
    P##R5 = rp[5]; \
    kp += 512; qp += 256; vp += 1024; rp += 24; \
    __builtin_amdgcn_sched_barrier(0); }

#define STEPQ(P) { \
    float r[6]; \
    r[0] = P##kA.x * sx + P##kA.y * sy; \
    r[1] = P##kA.z * sx + P##kA.w * sy; \
    r[2] = P##kB.x * sx + P##kB.y * sy; \
    r[3] = P##kB.z * sx + P##kB.w * sy; \
    r[4] = P##qv.x * sx + P##qv.y * sy; \
    r[5] = P##qv.z * sx + P##qv.w * sy; \
    dpp_reduce(r); \
    float c0 = fmaf(-P##R0.x, r[0], P##R3.w * P##vv.x); \
    float c1 = fmaf(-P##R0.z, c0, fmaf(-P##R0.y, r[1], P##R5.x * P##vv.y)); \
    float c2 = fmaf(-P##R1.z, c1, fmaf(-P##R1.y, c0, fmaf(-P##R1.x, r[2], P##R5.y * P##vv.z))); \
    float c3 = fmaf(-P##R2.w, c2, fmaf(-P##R2.z, c1, fmaf(-P##R2.y, c0, \
               fmaf(-P##R2.x, r[3], P##R5.z * P##vv.w)))); \
    float ot = fmaf(P##R3.y, c1, fmaf(P##R3.x, c0, P##R0.w * r[4])); \
    float ot1 = fmaf(P##R4.w, c3, fmaf(P##R4.z, c2, fmaf(P##R4.y, c1, \
                fmaf(P##R4.x, c0, P##R3.z * r[5])))); \
    float g0 = P##R1.w * c0, g1 = P##R1.w * c1; \
    sx = fmaf(c3, P##kB.z, fmaf(c2, P##kB.x, fmaf(g1, P##kA.z, fmaf(g0, P##kA.x, P##R3.z * sx)))); \
    sy = fmaf(c3, P##kB.w, fmaf(c2, P##kB.y, fmaf(g1, P##kA.w, fmaf(g0, P##kA.y, P##R3.z * sy)))); \
    if (lane == 0) { op[0] = ot; op[NTOT] = ot1; } \
    op += 2 * NTOT; }

  LOADQ(A)
  LOADQ(B)
  for (int it = 0; it < 255; ++it) {
    STEPQ(A) LOADQ(A)
    STEPQ(B) LOADQ(B)
  }
  STEPQ(A)
  STEPQ(B)
#undef LOADQ
#undef STEPQ
}

// ---------------- RMSNorm(o) * w * SiLU(gate); writes dense bf16 [M][1024]
__global__ __launch_bounds__(256) void post_norm_gate(const float* __restrict__ o,
                                                      const float* __restrict__ gate,
                                                      const float* __restrict__ w,
                                                      ushort* __restrict__ obf) {
  int rb = blockIdx.x;
  int bt = rb >> 2, h = rb & 3;
  int tid = threadIdx.x;
  size_t ob = (size_t)bt * NTOT + h * 256 + tid;
  float ov = o[ob];
  float ss = wave_sum(ov * ov);
  __shared__ float sred[4];
  if ((tid & 63) == 0) sred[tid >> 6] = ss;
  __syncthreads();
  float tot = sred[0] + sred[1] + sred[2] + sred[3];
  float rms = rsqrtf(tot * (1.f / 256.f) + 1e-5f);
  float gt = gate[(size_t)bt * NTOT + h * 256 + tid];
  float val = ov * rms * w[tid] * (gt / (1.f + expf(-gt)));
  obf[(size_t)bt * HID + h * 256 + tid] = f2bf(val);
}

extern "C" void kernel_launch(void* const* d_in, const int* in_sizes, int n_in,
                              void* d_out, int out_size, void* d_ws, size_t ws_size,
                              hipStream_t stream) {
  const float* hs      = (const float*)d_in[0];
  const float* Wq      = (const float*)d_in[1];
  const float* Wk      = (const float*)d_in[2];
  const float* Wv      = (const float*)d_in[3];
  const float* Wb      = (const float*)d_in[4];
  const float* Wa      = (const float*)d_in[5];
  const float* Wg      = (const float*)d_in[6];
  const float* Wo      = (const float*)d_in[7];
  const float* A_log   = (const float*)d_in[8];
  const float* dt_bias = (const float*)d_in[9];
  const float* wq_conv = (const float*)d_in[10];
  const float* wk_conv = (const float*)d_in[11];
  const float* wv_conv = (const float*)d_in[12];
  const float* o_w     = (const float*)d_in[13];
  float* out = (float*)d_out;

  const int B = 2, T = 1024, M = B * T;

  float* ws    = (float*)d_ws;
  float* qkvg  = ws;                          // M*4608 fp32; cols 0..1023 get o; 3584+ gate
  float* kbuf  = qkvg + (size_t)M * NTOT;     // M*1024 (k interleaved)
  float* vbuf  = kbuf + (size_t)M * 1024;     // M*2048 (v pair-major)
  float* betab = vbuf + (size_t)M * 2048;     // M*8
  float* gb    = betab + (size_t)M * 8;       // M*4 (gamma)
  float* recb  = gb + (size_t)M * 4;          // 4096*24 floats
  float* woTf  = recb + (size_t)4096 * 24;    // 1024*1024 bf16 = 524288 floats
  float* qbuf  = out;                         // M*512 scratch (q pair-interleaved)

  // time-disjoint bf16 aliases in kbuf/vbuf regions:
  ushort* bqkvgT = (ushort*)kbuf;
  ushort* hsb    = (ushort*)(vbuf + (size_t)524288);  // vbuf + 2MB
  ushort* woT    = (ushort*)woTf;                     // dedicated slot (hoisted to prep)
  ushort* obf    = (ushort*)vbuf;                     // after scan (v dead)

  // fused front-end: cast | weight transposes | beta/gamma projections
  prep<<<9728, 256, 0, stream>>>(hs, Wq, Wk, Wv, Wg, Wo, Wb, Wa, A_log, dt_bias,
                                 hsb, bqkvgT, woT, betab, gb);
  // fused projections (bf16 MFMA) -> packed fp32 [M,4608]
  gemm_bf16<<<dim3(NTOT / 128, M / 128), 256, 0, stream>>>(hsb, bqkvgT, qkvg, HID, NTOT);
  // fused conv + SiLU (+ l2norm q,k)
  conv_all<<<2 * 64 * 14, 256, 0, stream>>>(qkvg, wq_conv, wk_conv, wv_conv,
                                            qbuf, kbuf, vbuf, T);
  // 2-step coefficient records
  cross_dots2<<<M * H / 8, 256, 0, stream>>>(kbuf, qbuf, betab, gb, recb);
  // batched scan -> o into qkvg cols 0..1023
  scan2<<<512, 256, 0, stream>>>((const float4*)kbuf, (const float4*)qbuf,
                                 (const float4*)vbuf, (const float4*)recb, qkvg);
  // epilogue + output projection
  post_norm_gate<<<M * H, 256, 0, stream>>>(qkvg, qkvg + 3584, o_w, obf);
  gemm_bf16<<<dim3(HID / 128, M / 128), 256, 0, stream>>>(obf, woT, out, HID, HID);
}